// Round 16
// baseline (719.149 us; speedup 1.0000x reference)
//
#include <hip/hip_runtime.h>
#include <cstdint>
#include <cstddef>

#define NNODES 50000

typedef __attribute__((ext_vector_type(8))) short short8;
typedef __attribute__((ext_vector_type(4))) float f32x4;
typedef __attribute__((ext_vector_type(4))) unsigned short u16x4;
typedef __attribute__((ext_vector_type(2))) unsigned short u16x2;
typedef __attribute__((ext_vector_type(4))) unsigned int u32x4;

__device__ __forceinline__ unsigned short f2bf(float f) {
  unsigned u = __builtin_bit_cast(unsigned, f);
  u = u + 0x7FFFu + ((u >> 16) & 1u);
  return (unsigned short)(u >> 16);
}
__device__ __forceinline__ float bf2f(unsigned short u) {
  return __builtin_bit_cast(float, (unsigned)u << 16);
}
// HW packed fp32->bf16 (RNE), gfx950: no builtin, inline asm (T12 recipe)
__device__ __forceinline__ unsigned cvtpk(float lo, float hi) {
  unsigned r;
  asm("v_cvt_pk_bf16_f32 %0, %1, %2" : "=v"(r) : "v"(lo), "v"(hi));
  return r;
}

// ---------------- batched degree count (grid.y = scale) ----------------
__global__ void deg_count3_kernel(const int* __restrict__ e0, const int* __restrict__ e1,
                                  const int* __restrict__ e2, int E0, int E1, int E2,
                                  int* __restrict__ deg, int n) {
  int s = blockIdx.y;
  const int* ei = s == 0 ? e0 : (s == 1 ? e1 : e2);
  int E = s == 0 ? E0 : (s == 1 ? E1 : E2);
  int i = blockIdx.x * blockDim.x + threadIdx.x;
  if (i < E) atomicAdd(&deg[(size_t)s * n + ei[E + i]], 1);
}

__global__ void deg_finish_kernel(const int* __restrict__ deg, float* __restrict__ dinv, int n) {
  int i = blockIdx.x * blockDim.x + threadIdx.x;
  if (i < n) dinv[i] = rsqrtf((float)deg[i] + 1.0f);  // +1 self-loop
}

// ---------------- batched pool-weight accumulate ----------------
__global__ void csum_count3_kernel(const int* __restrict__ e0, const int* __restrict__ e1,
                                   const int* __restrict__ e2, int E0, int E1, int E2,
                                   const float* __restrict__ dinv_all, float* __restrict__ csum,
                                   int n) {
  int s = blockIdx.y;
  const int* ei = s == 0 ? e0 : (s == 1 ? e1 : e2);
  int E = s == 0 ? E0 : (s == 1 ? E1 : E2);
  int i = blockIdx.x * blockDim.x + threadIdx.x;
  if (i < E)
    unsafeAtomicAdd(&csum[(size_t)s * n + ei[i]], dinv_all[(size_t)s * n + ei[E + i]]);
}

__global__ void c_finish_kernel(const float* __restrict__ dinv, float* __restrict__ csum, int n) {
  int i = blockIdx.x * blockDim.x + threadIdx.x;
  if (i < n) csum[i] = dinv[i] * (dinv[i] + csum[i]);
}

// ---------------- two-level parallel scan: bsum -> bscan -> rowptr ----------------
__global__ void bsum_kernel(const int* __restrict__ deg, int* __restrict__ bsum, int n,
                            int nchunk) {
  int s = blockIdx.y, c = blockIdx.x;
  int i = c * 256 + threadIdx.x;
  int v = (i < n) ? deg[(size_t)s * n + i] : 0;
  __shared__ int red[256];
  red[threadIdx.x] = v;
  __syncthreads();
  for (int o = 128; o > 0; o >>= 1) {
    if (threadIdx.x < o) red[threadIdx.x] += red[threadIdx.x + o];
    __syncthreads();
  }
  if (threadIdx.x == 0) bsum[s * nchunk + c] = red[0];
}

__global__ void bscan_kernel(int* __restrict__ bsum, int nchunk) {  // grid 3
  int s = blockIdx.x;
  __shared__ int tmp[256];
  int v = (threadIdx.x < nchunk) ? bsum[s * nchunk + threadIdx.x] : 0;
  tmp[threadIdx.x] = v;
  __syncthreads();
  for (int o = 1; o < 256; o <<= 1) {
    int t = (threadIdx.x >= o) ? tmp[threadIdx.x - o] : 0;
    __syncthreads();
    tmp[threadIdx.x] += t;
    __syncthreads();
  }
  if (threadIdx.x < nchunk) bsum[s * nchunk + threadIdx.x] = tmp[threadIdx.x] - v;  // exclusive
}

__global__ void rowptr_kernel(const int* __restrict__ deg, const int* __restrict__ bsum,
                              int* __restrict__ rowptr, int* __restrict__ cursor, int n,
                              int nchunk) {
  int s = blockIdx.y, c = blockIdx.x;
  int i = c * 256 + threadIdx.x;
  int v = (i < n) ? deg[(size_t)s * n + i] : 0;
  __shared__ int tmp[256];
  tmp[threadIdx.x] = v;
  __syncthreads();
  for (int o = 1; o < 256; o <<= 1) {
    int t = (threadIdx.x >= o) ? tmp[threadIdx.x - o] : 0;
    __syncthreads();
    tmp[threadIdx.x] += t;
    __syncthreads();
  }
  int incl = tmp[threadIdx.x] + bsum[s * nchunk + c];
  if (i < n) {
    rowptr[(size_t)s * (n + 1) + i + 1] = incl;
    cursor[(size_t)s * n + i] = incl - v;
  }
  if (i == 0) rowptr[(size_t)s * (n + 1)] = 0;
}

// ---------------- batched CSR fill ----------------
__global__ void csr_fill3_kernel(const int* __restrict__ e0, const int* __restrict__ e1,
                                 const int* __restrict__ e2, int E0, int E1, int E2,
                                 int* __restrict__ cursor, int* __restrict__ csr, int n) {
  int s = blockIdx.y;
  const int* ei = s == 0 ? e0 : (s == 1 ? e1 : e2);
  int E = s == 0 ? E0 : (s == 1 ? E1 : E2);
  int coff = (s > 0 ? E0 : 0) + (s > 1 ? E1 : 0);
  int i = blockIdx.x * blockDim.x + threadIdx.x;
  if (i < E) {
    int src = ei[i];
    int dst = ei[E + i];
    int pos = atomicAdd(&cursor[(size_t)s * n + dst], 1);
    csr[coff + pos] = src;
  }
}

// ---------------- batched weight transpose ----------------
__global__ void wt_all_kernel(const float* __restrict__ W0, const float* __restrict__ W1,
                              unsigned short* __restrict__ Wt) {
  int idx = blockIdx.x * blockDim.x + threadIdx.x;
  const int L0TOT = 3 * 262144;
  const int TOT = L0TOT + 3 * 32768;
  if (idx >= TOT) return;
  if (idx < L0TOT) {
    int s = idx / 262144, r = idx - s * 262144;
    int n = r >> 10, k = r & 1023;
    Wt[idx] = f2bf(W0[(size_t)s * 262144 + k * 256 + n]);
  } else {
    int j = idx - L0TOT;
    int s = j / 32768, r = j - s * 32768;
    int n = r >> 8, k = r & 255;
    Wt[idx] = f2bf(W1[(size_t)s * 32768 + k * 128 + n]);
  }
}

// ---------------- layer-0: 3-deep ring pipeline, gload_lds + counted vmcnt ----------------
// BM=64, BN=256, K=1024, NT=256 (4 waves, wave wc owns 64 cols). 3 x 48KB LDS ring.
// Steady state: vmcnt(24) -> tile t resident (issued 3 steps ago); tiles t+1,t+2 in flight
// (96KB/CU outstanding) -> load latency fully hidden; K-step paced by HBM BW only.
__global__ __launch_bounds__(256) void gemm_l0p_kernel(
    const float* __restrict__ A0, const float* __restrict__ A1, const float* __restrict__ A2,
    const unsigned short* __restrict__ Wt, unsigned short* __restrict__ H, size_t hStride,
    const float* __restrict__ dinv_all, int M) {
  constexpr int ABYTES = 64 * 64 * 4;    // 16KB fp32 A tile
  constexpr int BBYTES = 256 * 64 * 2;   // 32KB bf16 B tile
  constexpr int TILEB = ABYTES + BBYTES; // 48KB
  constexpr int NTILES = 16;             // K=1024/64

  __shared__ unsigned char lds[3 * TILEB];  // 144KB ring

  const int sc = blockIdx.y;
  const float* As = sc == 0 ? A0 : (sc == 1 ? A1 : A2);
  const unsigned short* Wts = Wt + (size_t)sc * 262144;
  unsigned short* Hs = H + (size_t)sc * hStride;
  const float* dinv = dinv_all + (size_t)sc * M;
  const int tid = threadIdx.x;
  const int lane = tid & 63;
  const int w = tid >> 6;
  const int wc = w;
  const int r0 = blockIdx.x * 64;

  auto issueTile = [&](int t, int buf) {
    const int k0 = t << 6;
    unsigned char* ldsb = lds + (size_t)buf * TILEB;
    // A: 4 issues/thread (16KB / 16B / 256thr)
#pragma unroll
    for (int i = 0; i < 4; i++) {
      int c = (w * 4 + i) * 64 + lane;  // 16B-chunk id, 64 rows x 16 chunks
      int row = c >> 4, j = c & 15;
      int gr = r0 + row;
      if (gr > M - 1) gr = M - 1;  // clamp: never stored
      const float* src = As + (size_t)gr * 1024 + k0 + ((j ^ (row & 7)) << 2);
      __builtin_amdgcn_global_load_lds(
          (const __attribute__((address_space(1))) void*)src,
          (__attribute__((address_space(3))) void*)(ldsb + (size_t)(w * 4 + i) * 1024),
          16, 0, 0);
    }
    // B: 8 issues/thread (32KB / 16B / 256thr)
#pragma unroll
    for (int i = 0; i < 8; i++) {
      int c = (w * 8 + i) * 64 + lane;  // 256 cols x 8 chunks
      int n = c >> 3, j = c & 7;
      const unsigned short* src = Wts + (size_t)n * 1024 + k0 + ((j ^ (n & 7)) << 3);
      __builtin_amdgcn_global_load_lds(
          (const __attribute__((address_space(1))) void*)src,
          (__attribute__((address_space(3))) void*)(ldsb + ABYTES + (size_t)(w * 8 + i) * 1024),
          16, 0, 0);
    }
  };

  f32x4 acc[4][4] = {};

  auto computeT = [&](int buf) {
    const float* AldsF = (const float*)(lds + (size_t)buf * TILEB);
    const unsigned short* Blds = (const unsigned short*)(lds + (size_t)buf * TILEB + ABYTES);
#pragma unroll
    for (int kk = 0; kk < 2; kk++) {
      const int t16 = kk * 4 + (lane >> 4);
      short8 af[4], bfr[4];
#pragma unroll
      for (int mi = 0; mi < 4; mi++) {
        int row = mi * 16 + (lane & 15);
        const float* bp = AldsF + row * 64;
        f32x4 u0 = *(const f32x4*)(bp + (((2 * t16) ^ (row & 7)) << 2));
        f32x4 u1 = *(const f32x4*)(bp + (((2 * t16 + 1) ^ (row & 7)) << 2));
        u32x4 p;
        p[0] = cvtpk(u0[0], u0[1]);
        p[1] = cvtpk(u0[2], u0[3]);
        p[2] = cvtpk(u1[0], u1[1]);
        p[3] = cvtpk(u1[2], u1[3]);
        af[mi] = __builtin_bit_cast(short8, p);
      }
#pragma unroll
      for (int ni = 0; ni < 4; ni++) {
        int n = wc * 64 + ni * 16 + (lane & 15);
        bfr[ni] = *(const short8*)(Blds + n * 64 + ((t16 ^ (n & 7)) << 3));
      }
#pragma unroll
      for (int mi = 0; mi < 4; mi++)
#pragma unroll
        for (int ni = 0; ni < 4; ni++)
          acc[mi][ni] =
              __builtin_amdgcn_mfma_f32_16x16x32_bf16(af[mi], bfr[ni], acc[mi][ni], 0, 0, 0);
    }
  };

  // prologue: 3 tiles in flight
  issueTile(0, 0);
  issueTile(1, 1);
  issueTile(2, 2);
  int bi = 0;
#pragma unroll 1
  for (int t = 0; t < NTILES; ++t) {
    // wait for tile t only; later tiles' loads stay in flight across the barrier (T4)
    if (t + 2 < NTILES) {
      asm volatile("s_waitcnt vmcnt(24)" ::: "memory");  // 2 tiles x 12 issues in flight
    } else if (t + 1 < NTILES) {
      asm volatile("s_waitcnt vmcnt(12)" ::: "memory");
    } else {
      asm volatile("s_waitcnt vmcnt(0)" ::: "memory");
    }
    asm volatile("s_barrier" ::: "memory");
    computeT(bi);
    asm volatile("s_waitcnt lgkmcnt(0)\ns_barrier" ::: "memory");  // buf reads complete
    if (t + 3 < NTILES) issueTile(t + 3, bi);
    bi = (bi == 2) ? 0 : bi + 1;
  }

  // C/D layout: col = lane&15, row = (lane>>4)*4 + reg
#pragma unroll
  for (int mi = 0; mi < 4; mi++) {
#pragma unroll
    for (int r = 0; r < 4; r++) {
      int gr = r0 + mi * 16 + (lane >> 4) * 4 + r;
      if (gr < M) {
        float di = dinv[gr];
#pragma unroll
        for (int ni = 0; ni < 4; ni++) {
          int col = wc * 64 + ni * 16 + (lane & 15);
          Hs[(size_t)gr * 256 + col] = f2bf(acc[mi][ni][r] * di);
        }
      }
    }
  }
}

// ---------------- layer-1 GEMM (r12 form): A+B gload_lds, 2 barriers/K-step ----------------
// BM=128, BN=128, K=256, NT=256, 32KB LDS.
__global__ __launch_bounds__(256) void gemm_l1_kernel(
    const unsigned short* __restrict__ A0, const unsigned short* __restrict__ A1,
    const unsigned short* __restrict__ A2, const unsigned short* __restrict__ Wt,
    unsigned short* __restrict__ H, size_t hStride, const float* __restrict__ dinv_all, int M) {
  constexpr int ABYTES = 128 * 64 * 2;  // 16KB
  __shared__ unsigned char lds[2 * ABYTES];  // A + B, 32KB
  unsigned short* Alds = (unsigned short*)lds;
  unsigned short* Blds = (unsigned short*)(lds + ABYTES);
  const int sc = blockIdx.y;
  const unsigned short* As = sc == 0 ? A0 : (sc == 1 ? A1 : A2);
  const unsigned short* Wts = Wt + (size_t)sc * 32768;
  unsigned short* Hs = H + (size_t)sc * hStride;
  const float* dinv = dinv_all + (size_t)sc * M;
  const int tid = threadIdx.x;
  const int lane = tid & 63;
  const int w = tid >> 6;
  const int wr = w >> 1;
  const int wc = w & 1;
  const int r0 = blockIdx.x * 128;

  f32x4 acc[4][4] = {};
  for (int t = 0; t < 4; ++t) {
    const int k0 = t << 6;
#pragma unroll
    for (int i = 0; i < 4; i++) {
      int c = (w * 4 + i) * 64 + lane;  // 128 rows x 8 chunks
      int row = c >> 3, j = c & 7;
      int gr = r0 + row;
      if (gr > M - 1) gr = M - 1;
      const unsigned short* src = As + (size_t)gr * 256 + k0 + ((j ^ (row & 7)) << 3);
      __builtin_amdgcn_global_load_lds(
          (const __attribute__((address_space(1))) void*)src,
          (__attribute__((address_space(3))) void*)(lds + (size_t)(w * 4 + i) * 1024),
          16, 0, 0);
    }
#pragma unroll
    for (int i = 0; i < 4; i++) {
      int c = (w * 4 + i) * 64 + lane;  // 128 cols x 8 chunks
      int n = c >> 3, j = c & 7;
      const unsigned short* src = Wts + (size_t)n * 256 + k0 + ((j ^ (n & 7)) << 3);
      __builtin_amdgcn_global_load_lds(
          (const __attribute__((address_space(1))) void*)src,
          (__attribute__((address_space(3))) void*)(lds + ABYTES + (size_t)(w * 4 + i) * 1024),
          16, 0, 0);
    }
    __syncthreads();
#pragma unroll
    for (int kk = 0; kk < 2; kk++) {
      const int t16 = kk * 4 + (lane >> 4);
      short8 af[4], bfr[4];
#pragma unroll
      for (int mi = 0; mi < 4; mi++) {
        int row = wr * 64 + mi * 16 + (lane & 15);
        af[mi] = *(const short8*)(Alds + row * 64 + ((t16 ^ (row & 7)) << 3));
      }
#pragma unroll
      for (int ni = 0; ni < 4; ni++) {
        int n = wc * 64 + ni * 16 + (lane & 15);
        bfr[ni] = *(const short8*)(Blds + n * 64 + ((t16 ^ (n & 7)) << 3));
      }
#pragma unroll
      for (int mi = 0; mi < 4; mi++)
#pragma unroll
        for (int ni = 0; ni < 4; ni++)
          acc[mi][ni] =
              __builtin_amdgcn_mfma_f32_16x16x32_bf16(af[mi], bfr[ni], acc[mi][ni], 0, 0, 0);
    }
    __syncthreads();
  }

#pragma unroll
  for (int mi = 0; mi < 4; mi++) {
#pragma unroll
    for (int r = 0; r < 4; r++) {
      int gr = r0 + wr * 64 + mi * 16 + (lane >> 4) * 4 + r;
      if (gr < M) {
        float di = dinv[gr];
#pragma unroll
        for (int ni = 0; ni < 4; ni++) {
          int col = wc * 64 + ni * 16 + (lane & 15);
          Hs[(size_t)gr * 128 + col] = f2bf(acc[mi][ni][r] * di);
        }
      }
    }
  }
}

// ---------------- batched CSR gather + BN + ReLU -> bf16 (grid.y = scale) ----------------
template <int VEC>
__device__ __forceinline__ void addrow(const unsigned short* __restrict__ p, float* acc) {
  if constexpr (VEC == 4) {
    u16x4 u = *(const u16x4*)p;
#pragma unroll
    for (int j = 0; j < 4; j++) acc[j] += bf2f(u[j]);
  } else {
    u16x2 u = *(const u16x2*)p;
    acc[0] += bf2f(u[0]);
    acc[1] += bf2f(u[1]);
  }
}

template <int VEC>
__global__ __launch_bounds__(256) void agg3_kernel(
    const unsigned short* __restrict__ Hb, size_t hStride,
    const int* __restrict__ rowptr, const int* __restrict__ csr, int E0, int E1,
    const float* __restrict__ dinv_all,
    const float* __restrict__ Bb, const float* __restrict__ g,
    const float* __restrict__ bt, const float* __restrict__ m,
    const float* __restrict__ v, unsigned short* __restrict__ X, size_t xStride, int n) {
  const int C = VEC * 64;
  const int sIdx = blockIdx.y;
  const unsigned short* Hs = Hb + (size_t)sIdx * hStride;
  unsigned short* Xs = X + (size_t)sIdx * xStride;
  const int* rp = rowptr + (size_t)sIdx * (n + 1);
  const int* cs = csr + (sIdx > 0 ? E0 : 0) + (sIdx > 1 ? E1 : 0);
  const float* dinv = dinv_all + (size_t)sIdx * n;
  const int lane = threadIdx.x & 63;
  const int w = threadIdx.x >> 6;
  const int ch = lane * VEC;
  float a[VEC], sh[VEC];
#pragma unroll
  for (int j = 0; j < VEC; j++) {
    float aa = g[sIdx * C + ch + j] * rsqrtf(v[sIdx * C + ch + j] + 1e-5f);
    a[j] = aa;
    sh[j] = (Bb[sIdx * C + ch + j] - m[sIdx * C + ch + j]) * aa + bt[sIdx * C + ch + j];
  }
  const int row = blockIdx.x * 4 + w;
  if (row >= n) return;
  float acc[VEC] = {};
  addrow<VEC>(Hs + (size_t)row * C + ch, acc);  // self
  int b0 = rp[row], b1 = rp[row + 1];
  int i = b0;
  for (; i + 8 <= b1; i += 8) {
    int s0 = cs[i], s1 = cs[i + 1], s2 = cs[i + 2], s3 = cs[i + 3];
    int s4 = cs[i + 4], s5 = cs[i + 5], s6 = cs[i + 6], s7 = cs[i + 7];
    addrow<VEC>(Hs + (size_t)s0 * C + ch, acc);
    addrow<VEC>(Hs + (size_t)s1 * C + ch, acc);
    addrow<VEC>(Hs + (size_t)s2 * C + ch, acc);
    addrow<VEC>(Hs + (size_t)s3 * C + ch, acc);
    addrow<VEC>(Hs + (size_t)s4 * C + ch, acc);
    addrow<VEC>(Hs + (size_t)s5 * C + ch, acc);
    addrow<VEC>(Hs + (size_t)s6 * C + ch, acc);
    addrow<VEC>(Hs + (size_t)s7 * C + ch, acc);
  }
  for (; i < b1; i++) addrow<VEC>(Hs + (size_t)cs[i] * C + ch, acc);
  float dd = dinv[row];
  if constexpr (VEC == 4) {
    u16x4 o;
#pragma unroll
    for (int j = 0; j < 4; j++) o[j] = f2bf(fmaxf(acc[j] * dd * a[j] + sh[j], 0.0f));
    *(u16x4*)(Xs + (size_t)row * C + ch) = o;
  } else {
    u16x2 o;
    o[0] = f2bf(fmaxf(acc[0] * dd * a[0] + sh[0], 0.0f));
    o[1] = f2bf(fmaxf(acc[1] * dd * a[1] + sh[1], 0.0f));
    *(u16x2*)(Xs + (size_t)row * C + ch) = o;
  }
}

// ---------------- batched weighted column-sum (C=128) ----------------
__global__ __launch_bounds__(256) void colsum3_kernel(const unsigned short* __restrict__ X,
                                                      size_t xStride,
                                                      const float* __restrict__ c_all,
                                                      float* __restrict__ pooled, int n) {
  const int s = blockIdx.y;
  const unsigned short* Xs = X + (size_t)s * xStride;
  const float* c = c_all + (size_t)s * n;
  const int ch = threadIdx.x & 127;
  const int half = threadIdx.x >> 7;
  float acc = 0.0f;
  for (int row = blockIdx.x * 2 + half; row < n; row += gridDim.x * 2)
    acc += c[row] * bf2f(Xs[(size_t)row * 128 + ch]);
  __shared__ float red[256];
  red[threadIdx.x] = acc;
  __syncthreads();
  if (threadIdx.x < 128)
    unsafeAtomicAdd(&pooled[s * 128 + ch], red[threadIdx.x] + red[threadIdx.x + 128]);
}

// ---------------- head: per-scale BN3((pooled/N)@W3 + b3), fuse, cls, reg ----------------
__global__ void head_kernel(const float* __restrict__ pooled, const float* __restrict__ W3p,
                            const float* __restrict__ B3p, const float* __restrict__ g3p,
                            const float* __restrict__ bt3p, const float* __restrict__ m3p,
                            const float* __restrict__ v3p, const float* __restrict__ fuse_W,
                            const float* __restrict__ fuse_b, const float* __restrict__ cls_W,
                            const float* __restrict__ cls_b, const float* __restrict__ reg_W,
                            const float* __restrict__ reg_b, float* __restrict__ out) {
  __shared__ float e[192];
  __shared__ float fused[64];
  int t = threadIdx.x;
  if (t < 192) {
    int s = t >> 6, ch = t & 63;
    float acc = 0.0f;
    const float* W3 = W3p + (size_t)s * 128 * 64;
    const float* pv = pooled + s * 128;
    for (int k = 0; k < 128; k++) acc += pv[k] * W3[k * 64 + ch];
    float a3 = g3p[s * 64 + ch] * rsqrtf(v3p[s * 64 + ch] + 1e-5f);
    e[t] = (acc * (1.0f / (float)NNODES) + B3p[s * 64 + ch] - m3p[s * 64 + ch]) * a3 +
           bt3p[s * 64 + ch];
  }
  __syncthreads();
  if (t < 64) {
    float acc = fuse_b[t];
    for (int k = 0; k < 192; k++) acc += e[k] * fuse_W[k * 64 + t];
    fused[t] = fmaxf(acc, 0.0f);
  }
  __syncthreads();
  if (t < 10) {
    float acc = cls_b[t];
    for (int k = 0; k < 64; k++) acc += fused[k] * cls_W[k * 10 + t];
    out[t] = acc;
  }
  if (t == 64) {
    float acc = reg_b[0];
    for (int k = 0; k < 64; k++) acc += fused[k] * reg_W[k];
    out[10] = 1.0f / (1.0f + expf(-acc));
  }
}

extern "C" void kernel_launch(void* const* d_in, const int* in_sizes, int n_in,
                              void* d_out, int out_size, void* d_ws, size_t ws_size,
                              hipStream_t stream) {
  const int N = NNODES;
  const int NCHUNK = (N + 255) / 256;  // 196
  const float* xs[3] = {(const float*)d_in[0], (const float*)d_in[1], (const float*)d_in[2]};
  const int* eis[3] = {(const int*)d_in[3], (const int*)d_in[4], (const int*)d_in[5]};
  int Es[3];
  for (int s = 0; s < 3; s++) Es[s] = in_sizes[3 + s] / 2;
  int maxE = Es[0] > Es[1] ? Es[0] : Es[1];
  if (Es[2] > maxE) maxE = Es[2];

  const float* Wp[2]  = {(const float*)d_in[6],  (const float*)d_in[12]};
  const float* Bp[2]  = {(const float*)d_in[7],  (const float*)d_in[13]};
  const float* gp[2]  = {(const float*)d_in[8],  (const float*)d_in[14]};
  const float* btp[2] = {(const float*)d_in[9],  (const float*)d_in[15]};
  const float* mp[2]  = {(const float*)d_in[10], (const float*)d_in[16]};
  const float* vp[2]  = {(const float*)d_in[11], (const float*)d_in[17]};
  const float* W3p  = (const float*)d_in[18];
  const float* B3p  = (const float*)d_in[19];
  const float* g3p  = (const float*)d_in[20];
  const float* bt3p = (const float*)d_in[21];
  const float* m3p  = (const float*)d_in[22];
  const float* v3p  = (const float*)d_in[23];
  const float* fuse_W = (const float*)d_in[24];
  const float* fuse_b = (const float*)d_in[25];
  const float* cls_W  = (const float*)d_in[26];
  const float* cls_b  = (const float*)d_in[27];
  const float* reg_W  = (const float*)d_in[28];
  const float* reg_b  = (const float*)d_in[29];

  size_t off = 0;
  auto alloc = [&](size_t nbytes) {
    char* p = (char*)d_ws + off;
    off += (nbytes + 255) & ~(size_t)255;
    return (void*)p;
  };
  int*   deg      = (int*)alloc(3 * (size_t)N * 4);
  float* dinv_all = (float*)alloc(3 * (size_t)N * 4);
  float* c_all    = (float*)alloc(3 * (size_t)N * 4);
  float* pooled   = (float*)alloc(3 * 128 * 4);
  int*   bsum     = (int*)alloc(3 * (size_t)NCHUNK * 4);
  int*   rowptr   = (int*)alloc(3 * (size_t)(N + 1) * 4);
  int*   cursor   = (int*)alloc(3 * (size_t)N * 4);
  int*   csr      = (int*)alloc((size_t)(Es[0] + Es[1] + Es[2]) * 4);
  unsigned short* Hbuf = (unsigned short*)alloc(3 * (size_t)N * 256 * 2);  // 76.8 MB
  unsigned short* Xbf  = (unsigned short*)alloc(3 * (size_t)N * 256 * 2);  // 76.8 MB
  unsigned short* Wt   = (unsigned short*)alloc((size_t)(3 * 262144 + 3 * 32768) * 2);
  (void)ws_size; (void)n_in; (void)out_size;

  const size_t HS = (size_t)N * 256;  // per-scale stride for Hbuf/Xbf (elements)

  hipMemsetAsync(deg, 0, 3 * (size_t)N * 4, stream);
  hipMemsetAsync(c_all, 0, 3 * (size_t)N * 4, stream);
  hipMemsetAsync(pooled, 0, 3 * 128 * 4, stream);

  // ---- graph prep (all scales batched; parallel two-level scan) ----
  dim3 eg((maxE + 255) / 256, 3);
  deg_count3_kernel<<<eg, 256, 0, stream>>>(eis[0], eis[1], eis[2], Es[0], Es[1], Es[2], deg, N);
  deg_finish_kernel<<<(3 * N + 255) / 256, 256, 0, stream>>>(deg, dinv_all, 3 * N);
  csum_count3_kernel<<<eg, 256, 0, stream>>>(eis[0], eis[1], eis[2], Es[0], Es[1], Es[2],
                                             dinv_all, c_all, N);
  c_finish_kernel<<<(3 * N + 255) / 256, 256, 0, stream>>>(dinv_all, c_all, 3 * N);
  bsum_kernel<<<dim3(NCHUNK, 3), 256, 0, stream>>>(deg, bsum, N, NCHUNK);
  bscan_kernel<<<3, 256, 0, stream>>>(bsum, NCHUNK);
  rowptr_kernel<<<dim3(NCHUNK, 3), 256, 0, stream>>>(deg, bsum, rowptr, cursor, N, NCHUNK);
  csr_fill3_kernel<<<eg, 256, 0, stream>>>(eis[0], eis[1], eis[2], Es[0], Es[1], Es[2], cursor,
                                           csr, N);
  wt_all_kernel<<<(3 * 262144 + 3 * 32768 + 255) / 256, 256, 0, stream>>>(Wp[0], Wp[1], Wt);

  // ---- layer 0: K=1024, C=256; BM=64 BN=256, 3-deep ring (144KB LDS) ----
  gemm_l0p_kernel<<<dim3((N + 63) / 64, 3), 256, 0, stream>>>(xs[0], xs[1], xs[2], Wt, Hbuf, HS,
                                                              dinv_all, N);
  agg3_kernel<4><<<dim3((N + 3) / 4, 3), 256, 0, stream>>>(
      Hbuf, HS, rowptr, csr, Es[0], Es[1], dinv_all, Bp[0], gp[0], btp[0], mp[0], vp[0], Xbf,
      HS, N);

  // ---- layer 1: K=256, C=128; BM=128 BN=128, 32KB LDS (r12 form) ----
  gemm_l1_kernel<<<dim3((N + 127) / 128, 3), 256, 0, stream>>>(Xbf, Xbf + HS, Xbf + 2 * HS,
                                                               Wt + 3 * 262144, Hbuf, HS,
                                                               dinv_all, N);
  agg3_kernel<2><<<dim3((N + 3) / 4, 3), 256, 0, stream>>>(
      Hbuf, HS, rowptr, csr, Es[0], Es[1], dinv_all, Bp[1], gp[1], btp[1], mp[1], vp[1], Xbf,
      HS, N);

  // ---- layer 3 collapsed: pooled[s] = sum_j c[j] * X2[j] ----
  colsum3_kernel<<<dim3(512, 3), 256, 0, stream>>>(Xbf, HS, c_all, pooled, N);

  head_kernel<<<1, 192, 0, stream>>>(pooled, W3p, B3p, g3p, bt3p, m3p, v3p, fuse_W, fuse_b,
                                     cls_W, cls_b, reg_W, reg_b, (float*)d_out);
}

// Round 17
// 622.731 us; speedup vs baseline: 1.1548x; 1.1548x over previous
//
#include <hip/hip_runtime.h>
#include <cstdint>
#include <cstddef>

#define NNODES 50000

typedef __attribute__((ext_vector_type(8))) short short8;
typedef __attribute__((ext_vector_type(4))) float f32x4;
typedef __attribute__((ext_vector_type(4))) unsigned short u16x4;
typedef __attribute__((ext_vector_type(2))) unsigned short u16x2;
typedef __attribute__((ext_vector_type(4))) unsigned int u32x4;

__device__ __forceinline__ unsigned short f2bf(float f) {
  unsigned u = __builtin_bit_cast(unsigned, f);
  u = u + 0x7FFFu + ((u >> 16) & 1u);
  return (unsigned short)(u >> 16);
}
__device__ __forceinline__ float bf2f(unsigned short u) {
  return __builtin_bit_cast(float, (unsigned)u << 16);
}
// HW packed fp32->bf16 (RNE), gfx950: no builtin, inline asm (T12 recipe)
__device__ __forceinline__ unsigned cvtpk(float lo, float hi) {
  unsigned r;
  asm("v_cvt_pk_bf16_f32 %0, %1, %2" : "=v"(r) : "v"(lo), "v"(hi));
  return r;
}

// ---------------- batched degree count (grid.y = scale) ----------------
__global__ void deg_count3_kernel(const int* __restrict__ e0, const int* __restrict__ e1,
                                  const int* __restrict__ e2, int E0, int E1, int E2,
                                  int* __restrict__ deg, int n) {
  int s = blockIdx.y;
  const int* ei = s == 0 ? e0 : (s == 1 ? e1 : e2);
  int E = s == 0 ? E0 : (s == 1 ? E1 : E2);
  int i = blockIdx.x * blockDim.x + threadIdx.x;
  if (i < E) atomicAdd(&deg[(size_t)s * n + ei[E + i]], 1);
}

__global__ void deg_finish_kernel(const int* __restrict__ deg, float* __restrict__ dinv, int n) {
  int i = blockIdx.x * blockDim.x + threadIdx.x;
  if (i < n) dinv[i] = rsqrtf((float)deg[i] + 1.0f);  // +1 self-loop
}

// ---------------- batched pool-weight accumulate ----------------
__global__ void csum_count3_kernel(const int* __restrict__ e0, const int* __restrict__ e1,
                                   const int* __restrict__ e2, int E0, int E1, int E2,
                                   const float* __restrict__ dinv_all, float* __restrict__ csum,
                                   int n) {
  int s = blockIdx.y;
  const int* ei = s == 0 ? e0 : (s == 1 ? e1 : e2);
  int E = s == 0 ? E0 : (s == 1 ? E1 : E2);
  int i = blockIdx.x * blockDim.x + threadIdx.x;
  if (i < E)
    unsafeAtomicAdd(&csum[(size_t)s * n + ei[i]], dinv_all[(size_t)s * n + ei[E + i]]);
}

__global__ void c_finish_kernel(const float* __restrict__ dinv, float* __restrict__ csum, int n) {
  int i = blockIdx.x * blockDim.x + threadIdx.x;
  if (i < n) csum[i] = dinv[i] * (dinv[i] + csum[i]);
}

// ---------------- two-level parallel scan: bsum -> bscan -> rowptr ----------------
__global__ void bsum_kernel(const int* __restrict__ deg, int* __restrict__ bsum, int n,
                            int nchunk) {
  int s = blockIdx.y, c = blockIdx.x;
  int i = c * 256 + threadIdx.x;
  int v = (i < n) ? deg[(size_t)s * n + i] : 0;
  __shared__ int red[256];
  red[threadIdx.x] = v;
  __syncthreads();
  for (int o = 128; o > 0; o >>= 1) {
    if (threadIdx.x < o) red[threadIdx.x] += red[threadIdx.x + o];
    __syncthreads();
  }
  if (threadIdx.x == 0) bsum[s * nchunk + c] = red[0];
}

__global__ void bscan_kernel(int* __restrict__ bsum, int nchunk) {  // grid 3
  int s = blockIdx.x;
  __shared__ int tmp[256];
  int v = (threadIdx.x < nchunk) ? bsum[s * nchunk + threadIdx.x] : 0;
  tmp[threadIdx.x] = v;
  __syncthreads();
  for (int o = 1; o < 256; o <<= 1) {
    int t = (threadIdx.x >= o) ? tmp[threadIdx.x - o] : 0;
    __syncthreads();
    tmp[threadIdx.x] += t;
    __syncthreads();
  }
  if (threadIdx.x < nchunk) bsum[s * nchunk + threadIdx.x] = tmp[threadIdx.x] - v;  // exclusive
}

__global__ void rowptr_kernel(const int* __restrict__ deg, const int* __restrict__ bsum,
                              int* __restrict__ rowptr, int* __restrict__ cursor, int n,
                              int nchunk) {
  int s = blockIdx.y, c = blockIdx.x;
  int i = c * 256 + threadIdx.x;
  int v = (i < n) ? deg[(size_t)s * n + i] : 0;
  __shared__ int tmp[256];
  tmp[threadIdx.x] = v;
  __syncthreads();
  for (int o = 1; o < 256; o <<= 1) {
    int t = (threadIdx.x >= o) ? tmp[threadIdx.x - o] : 0;
    __syncthreads();
    tmp[threadIdx.x] += t;
    __syncthreads();
  }
  int incl = tmp[threadIdx.x] + bsum[s * nchunk + c];
  if (i < n) {
    rowptr[(size_t)s * (n + 1) + i + 1] = incl;
    cursor[(size_t)s * n + i] = incl - v;
  }
  if (i == 0) rowptr[(size_t)s * (n + 1)] = 0;
}

// ---------------- batched CSR fill ----------------
__global__ void csr_fill3_kernel(const int* __restrict__ e0, const int* __restrict__ e1,
                                 const int* __restrict__ e2, int E0, int E1, int E2,
                                 int* __restrict__ cursor, int* __restrict__ csr, int n) {
  int s = blockIdx.y;
  const int* ei = s == 0 ? e0 : (s == 1 ? e1 : e2);
  int E = s == 0 ? E0 : (s == 1 ? E1 : E2);
  int coff = (s > 0 ? E0 : 0) + (s > 1 ? E1 : 0);
  int i = blockIdx.x * blockDim.x + threadIdx.x;
  if (i < E) {
    int src = ei[i];
    int dst = ei[E + i];
    int pos = atomicAdd(&cursor[(size_t)s * n + dst], 1);
    csr[coff + pos] = src;
  }
}

// ---------------- batched weight transpose ----------------
__global__ void wt_all_kernel(const float* __restrict__ W0, const float* __restrict__ W1,
                              unsigned short* __restrict__ Wt) {
  int idx = blockIdx.x * blockDim.x + threadIdx.x;
  const int L0TOT = 3 * 262144;
  const int TOT = L0TOT + 3 * 32768;
  if (idx >= TOT) return;
  if (idx < L0TOT) {
    int s = idx / 262144, r = idx - s * 262144;
    int n = r >> 10, k = r & 1023;
    Wt[idx] = f2bf(W0[(size_t)s * 262144 + k * 256 + n]);
  } else {
    int j = idx - L0TOT;
    int s = j / 32768, r = j - s * 32768;
    int n = r >> 8, k = r & 255;
    Wt[idx] = f2bf(W1[(size_t)s * 32768 + k * 128 + n]);
  }
}

// ---------------- m97-style MFMA GEMM via global_load_lds (r12-exact, best) ----------------
template <int A_FP32, int WR, int WC, int NT>
__global__ __launch_bounds__(NT) void gemm_lds3_kernel(
    const void* __restrict__ A0v, const void* __restrict__ A1v, const void* __restrict__ A2v,
    const unsigned short* __restrict__ Wt, int wtStride,
    unsigned short* __restrict__ H, size_t hStride,
    const float* __restrict__ dinv_all, int M, int K, int Nc) {
  constexpr int BM = WR * 64;
  constexpr int BN = WC * 64;
  constexpr int ABYTES = BM * 64 * (A_FP32 ? 4 : 2);
  constexpr int BBYTES = BN * 64 * 2;
  constexpr int AISS = ABYTES / (16 * NT);
  constexpr int BISS = BBYTES / (16 * NT);

  __shared__ unsigned char lds[ABYTES + BBYTES];
  float* AldsF = (float*)lds;
  unsigned short* AldsH = (unsigned short*)lds;
  unsigned short* Blds = (unsigned short*)(lds + ABYTES);

  const int sc = blockIdx.y;
  const void* Av = sc == 0 ? A0v : (sc == 1 ? A1v : A2v);
  const unsigned short* Wts = Wt + (size_t)sc * wtStride;
  unsigned short* Hs = H + (size_t)sc * hStride;
  const float* dinv = dinv_all + (size_t)sc * M;
  const int tid = threadIdx.x;
  const int lane = tid & 63;
  const int w = tid >> 6;
  const int wr = w / WC;
  const int wc = w - wr * WC;
  const int r0 = blockIdx.x * BM;
  const float* Af = (const float*)Av;
  const unsigned short* Ab = (const unsigned short*)Av;
  const int NT16 = K >> 6;

  f32x4 acc[4][4] = {};

  for (int t = 0; t < NT16; ++t) {
    const int k0 = t << 6;
#pragma unroll
    for (int i = 0; i < AISS; i++) {
      int c = (w * AISS + i) * 64 + lane;
      if constexpr (A_FP32) {
        int row = c >> 4, j = c & 15;
        int gr = r0 + row;
        if (gr > M - 1) gr = M - 1;  // clamp: never stored
        const float* src = Af + (size_t)gr * K + k0 + ((j ^ (row & 7)) << 2);
        __builtin_amdgcn_global_load_lds(
            (const __attribute__((address_space(1))) void*)src,
            (__attribute__((address_space(3))) void*)(lds + (size_t)(w * AISS + i) * 1024),
            16, 0, 0);
      } else {
        int row = c >> 3, j = c & 7;
        int gr = r0 + row;
        if (gr > M - 1) gr = M - 1;
        const unsigned short* src = Ab + (size_t)gr * K + k0 + ((j ^ (row & 7)) << 3);
        __builtin_amdgcn_global_load_lds(
            (const __attribute__((address_space(1))) void*)src,
            (__attribute__((address_space(3))) void*)(lds + (size_t)(w * AISS + i) * 1024),
            16, 0, 0);
      }
    }
#pragma unroll
    for (int i = 0; i < BISS; i++) {
      int c = (w * BISS + i) * 64 + lane;
      int n = c >> 3, j = c & 7;
      const unsigned short* src = Wts + (size_t)n * K + k0 + ((j ^ (n & 7)) << 3);
      __builtin_amdgcn_global_load_lds(
          (const __attribute__((address_space(1))) void*)src,
          (__attribute__((address_space(3))) void*)(lds + ABYTES + (size_t)(w * BISS + i) * 1024),
          16, 0, 0);
    }
    __syncthreads();

#pragma unroll
    for (int kk = 0; kk < 2; kk++) {
      const int t16 = kk * 4 + (lane >> 4);
      short8 af[4], bfr[4];
#pragma unroll
      for (int mi = 0; mi < 4; mi++) {
        int row = wr * 64 + mi * 16 + (lane & 15);
        if constexpr (A_FP32) {
          const float* bp = AldsF + row * 64;
          f32x4 u0 = *(const f32x4*)(bp + ((((2 * t16)) ^ (row & 7)) << 2));
          f32x4 u1 = *(const f32x4*)(bp + (((2 * t16 + 1) ^ (row & 7)) << 2));
          u32x4 p;
          p[0] = cvtpk(u0[0], u0[1]);
          p[1] = cvtpk(u0[2], u0[3]);
          p[2] = cvtpk(u1[0], u1[1]);
          p[3] = cvtpk(u1[2], u1[3]);
          af[mi] = __builtin_bit_cast(short8, p);
        } else {
          af[mi] = *(const short8*)(AldsH + row * 64 + ((t16 ^ (row & 7)) << 3));
        }
      }
#pragma unroll
      for (int ni = 0; ni < 4; ni++) {
        int n = wc * 64 + ni * 16 + (lane & 15);
        bfr[ni] = *(const short8*)(Blds + n * 64 + ((t16 ^ (n & 7)) << 3));
      }
#pragma unroll
      for (int mi = 0; mi < 4; mi++)
#pragma unroll
        for (int ni = 0; ni < 4; ni++)
          acc[mi][ni] =
              __builtin_amdgcn_mfma_f32_16x16x32_bf16(af[mi], bfr[ni], acc[mi][ni], 0, 0, 0);
    }
    __syncthreads();
  }

  // C/D layout: col = lane&15, row = (lane>>4)*4 + reg
#pragma unroll
  for (int mi = 0; mi < 4; mi++) {
#pragma unroll
    for (int r = 0; r < 4; r++) {
      int gr = r0 + wr * 64 + mi * 16 + (lane >> 4) * 4 + r;
      if (gr < M) {
        float di = dinv[gr];
#pragma unroll
        for (int ni = 0; ni < 4; ni++) {
          int col = wc * 64 + ni * 16 + (lane & 15);
          Hs[(size_t)gr * Nc + col] = f2bf(acc[mi][ni][r] * di);
        }
      }
    }
  }
}

// ---------------- batched CSR gather + BN (+ReLU->X | +pool) grid-strided -------------
template <int VEC>
__device__ __forceinline__ void addrow(const unsigned short* __restrict__ p, float* acc) {
  if constexpr (VEC == 4) {
    u16x4 u = *(const u16x4*)p;
#pragma unroll
    for (int j = 0; j < 4; j++) acc[j] += bf2f(u[j]);
  } else {
    u16x2 u = *(const u16x2*)p;
    acc[0] += bf2f(u[0]);
    acc[1] += bf2f(u[1]);
  }
}

// POOL=0: X[row] = relu(bn(agg)) bf16.  POOL=1 (VEC=2): pooled_rep[rep][s][ch] +=
// sum_rows c[row]*bn(agg) via LDS reduce + 8-replica atomics (X2 never materialized).
template <int VEC, int POOL>
__global__ __launch_bounds__(256) void agg3_kernel(
    const unsigned short* __restrict__ Hb, size_t hStride,
    const int* __restrict__ rowptr, const int* __restrict__ csr, int E0, int E1,
    const float* __restrict__ dinv_all,
    const float* __restrict__ Bb, const float* __restrict__ g,
    const float* __restrict__ bt, const float* __restrict__ m,
    const float* __restrict__ v, unsigned short* __restrict__ X, size_t xStride,
    const float* __restrict__ c_all, float* __restrict__ pooled_rep, int n) {
  const int C = VEC * 64;
  const int sIdx = blockIdx.y;
  const unsigned short* Hs = Hb + (size_t)sIdx * hStride;
  unsigned short* Xs = X + (size_t)sIdx * xStride;
  const int* rp = rowptr + (size_t)sIdx * (n + 1);
  const int* cs = csr + (sIdx > 0 ? E0 : 0) + (sIdx > 1 ? E1 : 0);
  const float* dinv = dinv_all + (size_t)sIdx * n;
  const float* cw = c_all + (size_t)sIdx * n;
  const int lane = threadIdx.x & 63;
  const int w = threadIdx.x >> 6;
  const int ch = lane * VEC;
  float a[VEC], sh[VEC];
#pragma unroll
  for (int j = 0; j < VEC; j++) {
    float aa = g[sIdx * C + ch + j] * rsqrtf(v[sIdx * C + ch + j] + 1e-5f);
    a[j] = aa;
    sh[j] = (Bb[sIdx * C + ch + j] - m[sIdx * C + ch + j]) * aa + bt[sIdx * C + ch + j];
  }
  float pool[VEC] = {};
  const int stride = gridDim.x * 4;
  for (int row = blockIdx.x * 4 + w; row < n; row += stride) {
    float acc[VEC] = {};
    addrow<VEC>(Hs + (size_t)row * C + ch, acc);  // self
    int b0 = rp[row], b1 = rp[row + 1];
    int i = b0;
    for (; i + 8 <= b1; i += 8) {
      int s0 = cs[i], s1 = cs[i + 1], s2 = cs[i + 2], s3 = cs[i + 3];
      int s4 = cs[i + 4], s5 = cs[i + 5], s6 = cs[i + 6], s7 = cs[i + 7];
      addrow<VEC>(Hs + (size_t)s0 * C + ch, acc);
      addrow<VEC>(Hs + (size_t)s1 * C + ch, acc);
      addrow<VEC>(Hs + (size_t)s2 * C + ch, acc);
      addrow<VEC>(Hs + (size_t)s3 * C + ch, acc);
      addrow<VEC>(Hs + (size_t)s4 * C + ch, acc);
      addrow<VEC>(Hs + (size_t)s5 * C + ch, acc);
      addrow<VEC>(Hs + (size_t)s6 * C + ch, acc);
      addrow<VEC>(Hs + (size_t)s7 * C + ch, acc);
    }
    for (; i < b1; i++) addrow<VEC>(Hs + (size_t)cs[i] * C + ch, acc);
    float dd = dinv[row];
    if constexpr (!POOL) {
      if constexpr (VEC == 4) {
        u16x4 o;
#pragma unroll
        for (int j = 0; j < 4; j++) o[j] = f2bf(fmaxf(acc[j] * dd * a[j] + sh[j], 0.0f));
        *(u16x4*)(Xs + (size_t)row * C + ch) = o;
      } else {
        u16x2 o;
        o[0] = f2bf(fmaxf(acc[0] * dd * a[0] + sh[0], 0.0f));
        o[1] = f2bf(fmaxf(acc[1] * dd * a[1] + sh[1], 0.0f));
        *(u16x2*)(Xs + (size_t)row * C + ch) = o;
      }
    } else {
      float cr = cw[row];
#pragma unroll
      for (int j = 0; j < VEC; j++)
        pool[j] += cr * fmaxf(acc[j] * dd * a[j] + sh[j], 0.0f);  // X2 = relu(bn(.))
    }
  }
  if constexpr (POOL) {
    __shared__ float red[4 * 128];
#pragma unroll
    for (int j = 0; j < VEC; j++) red[w * 128 + ch + j] = pool[j];
    __syncthreads();
    int t = threadIdx.x;
    if (t < 128) {
      float val = red[t] + red[128 + t] + red[256 + t] + red[384 + t];
      unsafeAtomicAdd(&pooled_rep[(((size_t)(blockIdx.x & 7) * 3 + sIdx) << 7) + t], val);
    }
  }
}

// ---------------- head: sum replicas; per-scale BN3((pooled/N)@W3+b3), fuse, cls, reg ----
__global__ void head_kernel(const float* __restrict__ pooled_rep, const float* __restrict__ W3p,
                            const float* __restrict__ B3p, const float* __restrict__ g3p,
                            const float* __restrict__ bt3p, const float* __restrict__ m3p,
                            const float* __restrict__ v3p, const float* __restrict__ fuse_W,
                            const float* __restrict__ fuse_b, const float* __restrict__ cls_W,
                            const float* __restrict__ cls_b, const float* __restrict__ reg_W,
                            const float* __restrict__ reg_b, float* __restrict__ out) {
  __shared__ float pv[3 * 128];
  __shared__ float e[192];
  __shared__ float fused[64];
  int t = threadIdx.x;
  // sum the 8 replicas: pv[s*128+k]
  for (int idx = t; idx < 384; idx += 192) {
    int s = idx >> 7, k = idx & 127;
    float acc = 0.0f;
#pragma unroll
    for (int r = 0; r < 8; r++) acc += pooled_rep[((r * 3 + s) << 7) + k];
    pv[idx] = acc;
  }
  __syncthreads();
  if (t < 192) {
    int s = t >> 6, ch = t & 63;
    float acc = 0.0f;
    const float* W3 = W3p + (size_t)s * 128 * 64;
    for (int k = 0; k < 128; k++) acc += pv[s * 128 + k] * W3[k * 64 + ch];
    float a3 = g3p[s * 64 + ch] * rsqrtf(v3p[s * 64 + ch] + 1e-5f);
    e[t] = (acc * (1.0f / (float)NNODES) + B3p[s * 64 + ch] - m3p[s * 64 + ch]) * a3 +
           bt3p[s * 64 + ch];
  }
  __syncthreads();
  if (t < 64) {
    float acc = fuse_b[t];
    for (int k = 0; k < 192; k++) acc += e[k] * fuse_W[k * 64 + t];
    fused[t] = fmaxf(acc, 0.0f);
  }
  __syncthreads();
  if (t < 10) {
    float acc = cls_b[t];
    for (int k = 0; k < 64; k++) acc += fused[k] * cls_W[k * 10 + t];
    out[t] = acc;
  }
  if (t == 64) {
    float acc = reg_b[0];
    for (int k = 0; k < 64; k++) acc += fused[k] * reg_W[k];
    out[10] = 1.0f / (1.0f + expf(-acc));
  }
}

extern "C" void kernel_launch(void* const* d_in, const int* in_sizes, int n_in,
                              void* d_out, int out_size, void* d_ws, size_t ws_size,
                              hipStream_t stream) {
  const int N = NNODES;
  const int NCHUNK = (N + 255) / 256;  // 196
  const float* xs[3] = {(const float*)d_in[0], (const float*)d_in[1], (const float*)d_in[2]};
  const int* eis[3] = {(const int*)d_in[3], (const int*)d_in[4], (const int*)d_in[5]};
  int Es[3];
  for (int s = 0; s < 3; s++) Es[s] = in_sizes[3 + s] / 2;
  int maxE = Es[0] > Es[1] ? Es[0] : Es[1];
  if (Es[2] > maxE) maxE = Es[2];

  const float* Wp[2]  = {(const float*)d_in[6],  (const float*)d_in[12]};
  const float* Bp[2]  = {(const float*)d_in[7],  (const float*)d_in[13]};
  const float* gp[2]  = {(const float*)d_in[8],  (const float*)d_in[14]};
  const float* btp[2] = {(const float*)d_in[9],  (const float*)d_in[15]};
  const float* mp[2]  = {(const float*)d_in[10], (const float*)d_in[16]};
  const float* vp[2]  = {(const float*)d_in[11], (const float*)d_in[17]};
  const float* W3p  = (const float*)d_in[18];
  const float* B3p  = (const float*)d_in[19];
  const float* g3p  = (const float*)d_in[20];
  const float* bt3p = (const float*)d_in[21];
  const float* m3p  = (const float*)d_in[22];
  const float* v3p  = (const float*)d_in[23];
  const float* fuse_W = (const float*)d_in[24];
  const float* fuse_b = (const float*)d_in[25];
  const float* cls_W  = (const float*)d_in[26];
  const float* cls_b  = (const float*)d_in[27];
  const float* reg_W  = (const float*)d_in[28];
  const float* reg_b  = (const float*)d_in[29];

  size_t off = 0;
  auto alloc = [&](size_t nbytes) {
    char* p = (char*)d_ws + off;
    off += (nbytes + 255) & ~(size_t)255;
    return (void*)p;
  };
  int*   deg        = (int*)alloc(3 * (size_t)N * 4);
  float* dinv_all   = (float*)alloc(3 * (size_t)N * 4);
  float* c_all      = (float*)alloc(3 * (size_t)N * 4);
  float* pooled_rep = (float*)alloc(8 * 3 * 128 * 4);  // 12KB replicas
  int*   bsum       = (int*)alloc(3 * (size_t)NCHUNK * 4);
  int*   rowptr     = (int*)alloc(3 * (size_t)(N + 1) * 4);
  int*   cursor     = (int*)alloc(3 * (size_t)N * 4);
  int*   csr        = (int*)alloc((size_t)(Es[0] + Es[1] + Es[2]) * 4);
  unsigned short* Hbuf = (unsigned short*)alloc(3 * (size_t)N * 256 * 2);  // 76.8 MB
  unsigned short* Xbf  = (unsigned short*)alloc(3 * (size_t)N * 256 * 2);  // 76.8 MB
  unsigned short* Wt   = (unsigned short*)alloc((size_t)(3 * 262144 + 3 * 32768) * 2);
  (void)ws_size; (void)n_in; (void)out_size;

  const size_t HS = (size_t)N * 256;  // per-scale stride for Hbuf/Xbf (elements)

  hipMemsetAsync(deg, 0, 3 * (size_t)N * 4, stream);
  hipMemsetAsync(c_all, 0, 3 * (size_t)N * 4, stream);
  hipMemsetAsync(pooled_rep, 0, 8 * 3 * 128 * 4, stream);

  // ---- graph prep (all scales batched; parallel two-level scan) ----
  dim3 eg((maxE + 255) / 256, 3);
  deg_count3_kernel<<<eg, 256, 0, stream>>>(eis[0], eis[1], eis[2], Es[0], Es[1], Es[2], deg, N);
  deg_finish_kernel<<<(3 * N + 255) / 256, 256, 0, stream>>>(deg, dinv_all, 3 * N);
  csum_count3_kernel<<<eg, 256, 0, stream>>>(eis[0], eis[1], eis[2], Es[0], Es[1], Es[2],
                                             dinv_all, c_all, N);
  c_finish_kernel<<<(3 * N + 255) / 256, 256, 0, stream>>>(dinv_all, c_all, 3 * N);
  bsum_kernel<<<dim3(NCHUNK, 3), 256, 0, stream>>>(deg, bsum, N, NCHUNK);
  bscan_kernel<<<3, 256, 0, stream>>>(bsum, NCHUNK);
  rowptr_kernel<<<dim3(NCHUNK, 3), 256, 0, stream>>>(deg, bsum, rowptr, cursor, N, NCHUNK);
  csr_fill3_kernel<<<eg, 256, 0, stream>>>(eis[0], eis[1], eis[2], Es[0], Es[1], Es[2], cursor,
                                           csr, N);
  wt_all_kernel<<<(3 * 262144 + 3 * 32768 + 255) / 256, 256, 0, stream>>>(Wp[0], Wp[1], Wt);

  // ---- layer 0: K=1024, C=256; BM=64 BN=256, 48KB LDS (r12-exact, best known) ----
  gemm_lds3_kernel<1, 1, 4, 256><<<dim3((N + 63) / 64, 3), 256, 0, stream>>>(
      xs[0], xs[1], xs[2], Wt, 262144, Hbuf, HS, dinv_all, N, 1024, 256);
  agg3_kernel<4, 0><<<dim3((N + 15) / 16, 3), 256, 0, stream>>>(
      Hbuf, HS, rowptr, csr, Es[0], Es[1], dinv_all, Bp[0], gp[0], btp[0], mp[0], vp[0], Xbf,
      HS, c_all, pooled_rep, N);

  // ---- layer 1: K=256, C=128; BM=128 BN=128, 32KB LDS (r12-exact) ----
  gemm_lds3_kernel<0, 2, 2, 256><<<dim3((N + 127) / 128, 3), 256, 0, stream>>>(
      Xbf, Xbf + HS, Xbf + 2 * HS, Wt + 3 * 262144, 32768, Hbuf, HS, dinv_all, N, 256, 128);
  // ---- layer 2 agg fused with layer-3 pooling (X2 never materialized) ----
  agg3_kernel<2, 1><<<dim3((N + 15) / 16, 3), 256, 0, stream>>>(
      Hbuf, HS, rowptr, csr, Es[0], Es[1], dinv_all, Bp[1], gp[1], btp[1], mp[1], vp[1], Xbf,
      HS, c_all, pooled_rep, N);

  head_kernel<<<1, 192, 0, stream>>>(pooled_rep, W3p, B3p, g3p, bt3p, m3p, v3p, fuse_W, fuse_b,
                                     cls_W, cls_b, reg_W, reg_b, (float*)d_out);
}

// Round 18
// 594.031 us; speedup vs baseline: 1.2106x; 1.0483x over previous
//
#include <hip/hip_runtime.h>
#include <cstdint>
#include <cstddef>

#define NNODES 50000

typedef __attribute__((ext_vector_type(8))) short short8;
typedef __attribute__((ext_vector_type(4))) float f32x4;
typedef __attribute__((ext_vector_type(4))) unsigned short u16x4;
typedef __attribute__((ext_vector_type(2))) unsigned short u16x2;
typedef __attribute__((ext_vector_type(4))) unsigned int u32x4;

__device__ __forceinline__ unsigned short f2bf(float f) {
  unsigned u = __builtin_bit_cast(unsigned, f);
  u = u + 0x7FFFu + ((u >> 16) & 1u);
  return (unsigned short)(u >> 16);
}
__device__ __forceinline__ float bf2f(unsigned short u) {
  return __builtin_bit_cast(float, (unsigned)u << 16);
}
// HW packed fp32->bf16 (RNE), gfx950: no builtin, inline asm (T12 recipe)
__device__ __forceinline__ unsigned cvtpk(float lo, float hi) {
  unsigned r;
  asm("v_cvt_pk_bf16_f32 %0, %1, %2" : "=v"(r) : "v"(lo), "v"(hi));
  return r;
}

// ---------------- batched degree count (grid.y = scale) ----------------
__global__ void deg_count3_kernel(const int* __restrict__ e0, const int* __restrict__ e1,
                                  const int* __restrict__ e2, int E0, int E1, int E2,
                                  int* __restrict__ deg, int n) {
  int s = blockIdx.y;
  const int* ei = s == 0 ? e0 : (s == 1 ? e1 : e2);
  int E = s == 0 ? E0 : (s == 1 ? E1 : E2);
  int i = blockIdx.x * blockDim.x + threadIdx.x;
  if (i < E) atomicAdd(&deg[(size_t)s * n + ei[E + i]], 1);
}

__global__ void deg_finish_kernel(const int* __restrict__ deg, float* __restrict__ dinv, int n) {
  int i = blockIdx.x * blockDim.x + threadIdx.x;
  if (i < n) dinv[i] = rsqrtf((float)deg[i] + 1.0f);  // +1 self-loop
}

__global__ void c_finish_kernel(const float* __restrict__ dinv, float* __restrict__ csum, int n) {
  int i = blockIdx.x * blockDim.x + threadIdx.x;
  if (i < n) csum[i] = dinv[i] * (dinv[i] + csum[i]);
}

// ---------------- two-level parallel scan: bsum -> bscan -> rowptr ----------------
__global__ void bsum_kernel(const int* __restrict__ deg, int* __restrict__ bsum, int n,
                            int nchunk) {
  int s = blockIdx.y, c = blockIdx.x;
  int i = c * 256 + threadIdx.x;
  int v = (i < n) ? deg[(size_t)s * n + i] : 0;
  __shared__ int red[256];
  red[threadIdx.x] = v;
  __syncthreads();
  for (int o = 128; o > 0; o >>= 1) {
    if (threadIdx.x < o) red[threadIdx.x] += red[threadIdx.x + o];
    __syncthreads();
  }
  if (threadIdx.x == 0) bsum[s * nchunk + c] = red[0];
}

__global__ void bscan_kernel(int* __restrict__ bsum, int nchunk) {  // grid 3
  int s = blockIdx.x;
  __shared__ int tmp[256];
  int v = (threadIdx.x < nchunk) ? bsum[s * nchunk + threadIdx.x] : 0;
  tmp[threadIdx.x] = v;
  __syncthreads();
  for (int o = 1; o < 256; o <<= 1) {
    int t = (threadIdx.x >= o) ? tmp[threadIdx.x - o] : 0;
    __syncthreads();
    tmp[threadIdx.x] += t;
    __syncthreads();
  }
  if (threadIdx.x < nchunk) bsum[s * nchunk + threadIdx.x] = tmp[threadIdx.x] - v;  // exclusive
}

__global__ void rowptr_kernel(const int* __restrict__ deg, const int* __restrict__ bsum,
                              int* __restrict__ rowptr, int* __restrict__ cursor, int n,
                              int nchunk) {
  int s = blockIdx.y, c = blockIdx.x;
  int i = c * 256 + threadIdx.x;
  int v = (i < n) ? deg[(size_t)s * n + i] : 0;
  __shared__ int tmp[256];
  tmp[threadIdx.x] = v;
  __syncthreads();
  for (int o = 1; o < 256; o <<= 1) {
    int t = (threadIdx.x >= o) ? tmp[threadIdx.x - o] : 0;
    __syncthreads();
    tmp[threadIdx.x] += t;
    __syncthreads();
  }
  int incl = tmp[threadIdx.x] + bsum[s * nchunk + c];
  if (i < n) {
    rowptr[(size_t)s * (n + 1) + i + 1] = incl;
    cursor[(size_t)s * n + i] = incl - v;
  }
  if (i == 0) rowptr[(size_t)s * (n + 1)] = 0;
}

// ---------------- batched CSR fill + fused pool-weight accumulate ----------------
// One edge pass: csr[pos]=src AND csum[src] += dinv[dst].
__global__ void csr_fill3_kernel(const int* __restrict__ e0, const int* __restrict__ e1,
                                 const int* __restrict__ e2, int E0, int E1, int E2,
                                 int* __restrict__ cursor, int* __restrict__ csr,
                                 const float* __restrict__ dinv_all, float* __restrict__ csum,
                                 int n) {
  int s = blockIdx.y;
  const int* ei = s == 0 ? e0 : (s == 1 ? e1 : e2);
  int E = s == 0 ? E0 : (s == 1 ? E1 : E2);
  int coff = (s > 0 ? E0 : 0) + (s > 1 ? E1 : 0);
  int i = blockIdx.x * blockDim.x + threadIdx.x;
  if (i < E) {
    int src = ei[i];
    int dst = ei[E + i];
    int pos = atomicAdd(&cursor[(size_t)s * n + dst], 1);
    csr[coff + pos] = src;
    unsafeAtomicAdd(&csum[(size_t)s * n + src], dinv_all[(size_t)s * n + dst]);
  }
}

// ---------------- batched weight transpose ----------------
__global__ void wt_all_kernel(const float* __restrict__ W0, const float* __restrict__ W1,
                              unsigned short* __restrict__ Wt) {
  int idx = blockIdx.x * blockDim.x + threadIdx.x;
  const int L0TOT = 3 * 262144;
  const int TOT = L0TOT + 3 * 32768;
  if (idx >= TOT) return;
  if (idx < L0TOT) {
    int s = idx / 262144, r = idx - s * 262144;
    int n = r >> 10, k = r & 1023;
    Wt[idx] = f2bf(W0[(size_t)s * 262144 + k * 256 + n]);
  } else {
    int j = idx - L0TOT;
    int s = j / 32768, r = j - s * 32768;
    int n = r >> 8, k = r & 255;
    Wt[idx] = f2bf(W1[(size_t)s * 32768 + k * 128 + n]);
  }
}

// ---------------- m97-style MFMA GEMM via global_load_lds (r12-exact, best) ----------------
template <int A_FP32, int WR, int WC, int NT>
__global__ __launch_bounds__(NT) void gemm_lds3_kernel(
    const void* __restrict__ A0v, const void* __restrict__ A1v, const void* __restrict__ A2v,
    const unsigned short* __restrict__ Wt, int wtStride,
    unsigned short* __restrict__ H, size_t hStride,
    const float* __restrict__ dinv_all, int M, int K, int Nc) {
  constexpr int BM = WR * 64;
  constexpr int BN = WC * 64;
  constexpr int ABYTES = BM * 64 * (A_FP32 ? 4 : 2);
  constexpr int BBYTES = BN * 64 * 2;
  constexpr int AISS = ABYTES / (16 * NT);
  constexpr int BISS = BBYTES / (16 * NT);

  __shared__ unsigned char lds[ABYTES + BBYTES];
  float* AldsF = (float*)lds;
  unsigned short* AldsH = (unsigned short*)lds;
  unsigned short* Blds = (unsigned short*)(lds + ABYTES);

  const int sc = blockIdx.y;
  const void* Av = sc == 0 ? A0v : (sc == 1 ? A1v : A2v);
  const unsigned short* Wts = Wt + (size_t)sc * wtStride;
  unsigned short* Hs = H + (size_t)sc * hStride;
  const float* dinv = dinv_all + (size_t)sc * M;
  const int tid = threadIdx.x;
  const int lane = tid & 63;
  const int w = tid >> 6;
  const int wr = w / WC;
  const int wc = w - wr * WC;
  const int r0 = blockIdx.x * BM;
  const float* Af = (const float*)Av;
  const unsigned short* Ab = (const unsigned short*)Av;
  const int NT16 = K >> 6;

  f32x4 acc[4][4] = {};

  for (int t = 0; t < NT16; ++t) {
    const int k0 = t << 6;
#pragma unroll
    for (int i = 0; i < AISS; i++) {
      int c = (w * AISS + i) * 64 + lane;
      if constexpr (A_FP32) {
        int row = c >> 4, j = c & 15;
        int gr = r0 + row;
        if (gr > M - 1) gr = M - 1;  // clamp: never stored
        const float* src = Af + (size_t)gr * K + k0 + ((j ^ (row & 7)) << 2);
        __builtin_amdgcn_global_load_lds(
            (const __attribute__((address_space(1))) void*)src,
            (__attribute__((address_space(3))) void*)(lds + (size_t)(w * AISS + i) * 1024),
            16, 0, 0);
      } else {
        int row = c >> 3, j = c & 7;
        int gr = r0 + row;
        if (gr > M - 1) gr = M - 1;
        const unsigned short* src = Ab + (size_t)gr * K + k0 + ((j ^ (row & 7)) << 3);
        __builtin_amdgcn_global_load_lds(
            (const __attribute__((address_space(1))) void*)src,
            (__attribute__((address_space(3))) void*)(lds + (size_t)(w * AISS + i) * 1024),
            16, 0, 0);
      }
    }
#pragma unroll
    for (int i = 0; i < BISS; i++) {
      int c = (w * BISS + i) * 64 + lane;
      int n = c >> 3, j = c & 7;
      const unsigned short* src = Wts + (size_t)n * K + k0 + ((j ^ (n & 7)) << 3);
      __builtin_amdgcn_global_load_lds(
          (const __attribute__((address_space(1))) void*)src,
          (__attribute__((address_space(3))) void*)(lds + ABYTES + (size_t)(w * BISS + i) * 1024),
          16, 0, 0);
    }
    __syncthreads();

#pragma unroll
    for (int kk = 0; kk < 2; kk++) {
      const int t16 = kk * 4 + (lane >> 4);
      short8 af[4], bfr[4];
#pragma unroll
      for (int mi = 0; mi < 4; mi++) {
        int row = wr * 64 + mi * 16 + (lane & 15);
        if constexpr (A_FP32) {
          const float* bp = AldsF + row * 64;
          f32x4 u0 = *(const f32x4*)(bp + ((((2 * t16)) ^ (row & 7)) << 2));
          f32x4 u1 = *(const f32x4*)(bp + (((2 * t16 + 1) ^ (row & 7)) << 2));
          u32x4 p;
          p[0] = cvtpk(u0[0], u0[1]);
          p[1] = cvtpk(u0[2], u0[3]);
          p[2] = cvtpk(u1[0], u1[1]);
          p[3] = cvtpk(u1[2], u1[3]);
          af[mi] = __builtin_bit_cast(short8, p);
        } else {
          af[mi] = *(const short8*)(AldsH + row * 64 + ((t16 ^ (row & 7)) << 3));
        }
      }
#pragma unroll
      for (int ni = 0; ni < 4; ni++) {
        int n = wc * 64 + ni * 16 + (lane & 15);
        bfr[ni] = *(const short8*)(Blds + n * 64 + ((t16 ^ (n & 7)) << 3));
      }
#pragma unroll
      for (int mi = 0; mi < 4; mi++)
#pragma unroll
        for (int ni = 0; ni < 4; ni++)
          acc[mi][ni] =
              __builtin_amdgcn_mfma_f32_16x16x32_bf16(af[mi], bfr[ni], acc[mi][ni], 0, 0, 0);
    }
    __syncthreads();
  }

  // C/D layout: col = lane&15, row = (lane>>4)*4 + reg
#pragma unroll
  for (int mi = 0; mi < 4; mi++) {
#pragma unroll
    for (int r = 0; r < 4; r++) {
      int gr = r0 + wr * 64 + mi * 16 + (lane >> 4) * 4 + r;
      if (gr < M) {
        float di = dinv[gr];
#pragma unroll
        for (int ni = 0; ni < 4; ni++) {
          int col = wc * 64 + ni * 16 + (lane & 15);
          Hs[(size_t)gr * Nc + col] = f2bf(acc[mi][ni][r] * di);
        }
      }
    }
  }
}

// ---------------- batched CSR gather + BN (+ReLU->X | +pool) grid-strided -------------
template <int VEC>
__device__ __forceinline__ void addrow(const unsigned short* __restrict__ p, float* acc) {
  if constexpr (VEC == 4) {
    u16x4 u = *(const u16x4*)p;
#pragma unroll
    for (int j = 0; j < 4; j++) acc[j] += bf2f(u[j]);
  } else {
    u16x2 u = *(const u16x2*)p;
    acc[0] += bf2f(u[0]);
    acc[1] += bf2f(u[1]);
  }
}

// POOL=0: X[row] = relu(bn(agg)) bf16.  POOL=1 (VEC=2): pooled_rep[rep][s][ch] +=
// sum_rows c[row]*relu(bn(agg)) via LDS reduce + 8-replica atomics.
template <int VEC, int POOL>
__global__ __launch_bounds__(256) void agg3_kernel(
    const unsigned short* __restrict__ Hb, size_t hStride,
    const int* __restrict__ rowptr, const int* __restrict__ csr, int E0, int E1,
    const float* __restrict__ dinv_all,
    const float* __restrict__ Bb, const float* __restrict__ g,
    const float* __restrict__ bt, const float* __restrict__ m,
    const float* __restrict__ v, unsigned short* __restrict__ X, size_t xStride,
    const float* __restrict__ c_all, float* __restrict__ pooled_rep, int n) {
  const int C = VEC * 64;
  const int sIdx = blockIdx.y;
  const unsigned short* Hs = Hb + (size_t)sIdx * hStride;
  unsigned short* Xs = X + (size_t)sIdx * xStride;
  const int* rp = rowptr + (size_t)sIdx * (n + 1);
  const int* cs = csr + (sIdx > 0 ? E0 : 0) + (sIdx > 1 ? E1 : 0);
  const float* dinv = dinv_all + (size_t)sIdx * n;
  const float* cw = c_all + (size_t)sIdx * n;
  const int lane = threadIdx.x & 63;
  const int w = threadIdx.x >> 6;
  const int ch = lane * VEC;
  float a[VEC], sh[VEC];
#pragma unroll
  for (int j = 0; j < VEC; j++) {
    float aa = g[sIdx * C + ch + j] * rsqrtf(v[sIdx * C + ch + j] + 1e-5f);
    a[j] = aa;
    sh[j] = (Bb[sIdx * C + ch + j] - m[sIdx * C + ch + j]) * aa + bt[sIdx * C + ch + j];
  }
  float pool[VEC] = {};
  const int stride = gridDim.x * 4;
  for (int row = blockIdx.x * 4 + w; row < n; row += stride) {
    float acc[VEC] = {};
    addrow<VEC>(Hs + (size_t)row * C + ch, acc);  // self
    int b0 = rp[row], b1 = rp[row + 1];
    int i = b0;
    for (; i + 8 <= b1; i += 8) {
      int s0 = cs[i], s1 = cs[i + 1], s2 = cs[i + 2], s3 = cs[i + 3];
      int s4 = cs[i + 4], s5 = cs[i + 5], s6 = cs[i + 6], s7 = cs[i + 7];
      addrow<VEC>(Hs + (size_t)s0 * C + ch, acc);
      addrow<VEC>(Hs + (size_t)s1 * C + ch, acc);
      addrow<VEC>(Hs + (size_t)s2 * C + ch, acc);
      addrow<VEC>(Hs + (size_t)s3 * C + ch, acc);
      addrow<VEC>(Hs + (size_t)s4 * C + ch, acc);
      addrow<VEC>(Hs + (size_t)s5 * C + ch, acc);
      addrow<VEC>(Hs + (size_t)s6 * C + ch, acc);
      addrow<VEC>(Hs + (size_t)s7 * C + ch, acc);
    }
    for (; i < b1; i++) addrow<VEC>(Hs + (size_t)cs[i] * C + ch, acc);
    float dd = dinv[row];
    if constexpr (!POOL) {
      if constexpr (VEC == 4) {
        u16x4 o;
#pragma unroll
        for (int j = 0; j < 4; j++) o[j] = f2bf(fmaxf(acc[j] * dd * a[j] + sh[j], 0.0f));
        *(u16x4*)(Xs + (size_t)row * C + ch) = o;
      } else {
        u16x2 o;
        o[0] = f2bf(fmaxf(acc[0] * dd * a[0] + sh[0], 0.0f));
        o[1] = f2bf(fmaxf(acc[1] * dd * a[1] + sh[1], 0.0f));
        *(u16x2*)(Xs + (size_t)row * C + ch) = o;
      }
    } else {
      float cr = cw[row];
#pragma unroll
      for (int j = 0; j < VEC; j++)
        pool[j] += cr * fmaxf(acc[j] * dd * a[j] + sh[j], 0.0f);  // X2 = relu(bn(.))
    }
  }
  if constexpr (POOL) {
    __shared__ float red[4 * 128];
#pragma unroll
    for (int j = 0; j < VEC; j++) red[w * 128 + ch + j] = pool[j];
    __syncthreads();
    int t = threadIdx.x;
    if (t < 128) {
      float val = red[t] + red[128 + t] + red[256 + t] + red[384 + t];
      unsafeAtomicAdd(&pooled_rep[(((size_t)(blockIdx.x & 7) * 3 + sIdx) << 7) + t], val);
    }
  }
}

// ---------------- head: sum replicas; per-scale BN3((pooled/N)@W3+b3), fuse, cls, reg ----
__global__ void head_kernel(const float* __restrict__ pooled_rep, const float* __restrict__ W3p,
                            const float* __restrict__ B3p, const float* __restrict__ g3p,
                            const float* __restrict__ bt3p, const float* __restrict__ m3p,
                            const float* __restrict__ v3p, const float* __restrict__ fuse_W,
                            const float* __restrict__ fuse_b, const float* __restrict__ cls_W,
                            const float* __restrict__ cls_b, const float* __restrict__ reg_W,
                            const float* __restrict__ reg_b, float* __restrict__ out) {
  __shared__ float pv[3 * 128];
  __shared__ float e[192];
  __shared__ float fused[64];
  int t = threadIdx.x;
  for (int idx = t; idx < 384; idx += 192) {
    int s = idx >> 7, k = idx & 127;
    float acc = 0.0f;
#pragma unroll
    for (int r = 0; r < 8; r++) acc += pooled_rep[((r * 3 + s) << 7) + k];
    pv[idx] = acc;
  }
  __syncthreads();
  if (t < 192) {
    int s = t >> 6, ch = t & 63;
    float acc = 0.0f;
    const float* W3 = W3p + (size_t)s * 128 * 64;
    for (int k = 0; k < 128; k++) acc += pv[s * 128 + k] * W3[k * 64 + ch];
    float a3 = g3p[s * 64 + ch] * rsqrtf(v3p[s * 64 + ch] + 1e-5f);
    e[t] = (acc * (1.0f / (float)NNODES) + B3p[s * 64 + ch] - m3p[s * 64 + ch]) * a3 +
           bt3p[s * 64 + ch];
  }
  __syncthreads();
  if (t < 64) {
    float acc = fuse_b[t];
    for (int k = 0; k < 192; k++) acc += e[k] * fuse_W[k * 64 + t];
    fused[t] = fmaxf(acc, 0.0f);
  }
  __syncthreads();
  if (t < 10) {
    float acc = cls_b[t];
    for (int k = 0; k < 64; k++) acc += fused[k] * cls_W[k * 10 + t];
    out[t] = acc;
  }
  if (t == 64) {
    float acc = reg_b[0];
    for (int k = 0; k < 64; k++) acc += fused[k] * reg_W[k];
    out[10] = 1.0f / (1.0f + expf(-acc));
  }
}

extern "C" void kernel_launch(void* const* d_in, const int* in_sizes, int n_in,
                              void* d_out, int out_size, void* d_ws, size_t ws_size,
                              hipStream_t stream) {
  const int N = NNODES;
  const int NCHUNK = (N + 255) / 256;  // 196
  const float* xs[3] = {(const float*)d_in[0], (const float*)d_in[1], (const float*)d_in[2]};
  const int* eis[3] = {(const int*)d_in[3], (const int*)d_in[4], (const int*)d_in[5]};
  int Es[3];
  for (int s = 0; s < 3; s++) Es[s] = in_sizes[3 + s] / 2;
  int maxE = Es[0] > Es[1] ? Es[0] : Es[1];
  if (Es[2] > maxE) maxE = Es[2];

  const float* Wp[2]  = {(const float*)d_in[6],  (const float*)d_in[12]};
  const float* Bp[2]  = {(const float*)d_in[7],  (const float*)d_in[13]};
  const float* gp[2]  = {(const float*)d_in[8],  (const float*)d_in[14]};
  const float* btp[2] = {(const float*)d_in[9],  (const float*)d_in[15]};
  const float* mp[2]  = {(const float*)d_in[10], (const float*)d_in[16]};
  const float* vp[2]  = {(const float*)d_in[11], (const float*)d_in[17]};
  const float* W3p  = (const float*)d_in[18];
  const float* B3p  = (const float*)d_in[19];
  const float* g3p  = (const float*)d_in[20];
  const float* bt3p = (const float*)d_in[21];
  const float* m3p  = (const float*)d_in[22];
  const float* v3p  = (const float*)d_in[23];
  const float* fuse_W = (const float*)d_in[24];
  const float* fuse_b = (const float*)d_in[25];
  const float* cls_W  = (const float*)d_in[26];
  const float* cls_b  = (const float*)d_in[27];
  const float* reg_W  = (const float*)d_in[28];
  const float* reg_b  = (const float*)d_in[29];

  size_t off = 0;
  auto alloc = [&](size_t nbytes) {
    char* p = (char*)d_ws + off;
    off += (nbytes + 255) & ~(size_t)255;
    return (void*)p;
  };
  // zero-init region (contiguous: one memset covers deg + c_all + pooled_rep)
  size_t zOff = off;
  int*   deg        = (int*)alloc(3 * (size_t)N * 4);
  float* c_all      = (float*)alloc(3 * (size_t)N * 4);
  float* pooled_rep = (float*)alloc(8 * 3 * 128 * 4);
  size_t zBytes = off - zOff;
  float* dinv_all   = (float*)alloc(3 * (size_t)N * 4);
  int*   bsum       = (int*)alloc(3 * (size_t)NCHUNK * 4);
  int*   rowptr     = (int*)alloc(3 * (size_t)(N + 1) * 4);
  int*   cursor     = (int*)alloc(3 * (size_t)N * 4);
  int*   csr        = (int*)alloc((size_t)(Es[0] + Es[1] + Es[2]) * 4);
  unsigned short* Hbuf = (unsigned short*)alloc(3 * (size_t)N * 256 * 2);  // 76.8 MB
  unsigned short* Xbf  = (unsigned short*)alloc(3 * (size_t)N * 256 * 2);  // 76.8 MB
  unsigned short* Wt   = (unsigned short*)alloc((size_t)(3 * 262144 + 3 * 32768) * 2);
  (void)ws_size; (void)n_in; (void)out_size;

  const size_t HS = (size_t)N * 256;  // per-scale stride for Hbuf/Xbf (elements)

  hipMemsetAsync((char*)d_ws + zOff, 0, zBytes, stream);  // deg + c_all + pooled_rep

  // ---- graph prep (all scales batched; parallel two-level scan; csum fused in fill) ----
  dim3 eg((maxE + 255) / 256, 3);
  deg_count3_kernel<<<eg, 256, 0, stream>>>(eis[0], eis[1], eis[2], Es[0], Es[1], Es[2], deg, N);
  deg_finish_kernel<<<(3 * N + 255) / 256, 256, 0, stream>>>(deg, dinv_all, 3 * N);
  bsum_kernel<<<dim3(NCHUNK, 3), 256, 0, stream>>>(deg, bsum, N, NCHUNK);
  bscan_kernel<<<3, 256, 0, stream>>>(bsum, NCHUNK);
  rowptr_kernel<<<dim3(NCHUNK, 3), 256, 0, stream>>>(deg, bsum, rowptr, cursor, N, NCHUNK);
  csr_fill3_kernel<<<eg, 256, 0, stream>>>(eis[0], eis[1], eis[2], Es[0], Es[1], Es[2], cursor,
                                           csr, dinv_all, c_all, N);
  c_finish_kernel<<<(3 * N + 255) / 256, 256, 0, stream>>>(dinv_all, c_all, 3 * N);
  wt_all_kernel<<<(3 * 262144 + 3 * 32768 + 255) / 256, 256, 0, stream>>>(Wp[0], Wp[1], Wt);

  // ---- layer 0: K=1024, C=256; BM=64 BN=256, 48KB LDS (r12-exact) ----
  gemm_lds3_kernel<1, 1, 4, 256><<<dim3((N + 63) / 64, 3), 256, 0, stream>>>(
      xs[0], xs[1], xs[2], Wt, 262144, Hbuf, HS, dinv_all, N, 1024, 256);
  agg3_kernel<4, 0><<<dim3((N + 15) / 16, 3), 256, 0, stream>>>(
      Hbuf, HS, rowptr, csr, Es[0], Es[1], dinv_all, Bp[0], gp[0], btp[0], mp[0], vp[0], Xbf,
      HS, c_all, pooled_rep, N);

  // ---- layer 1: K=256, C=128; BM=128 BN=128, 32KB LDS (r12-exact) ----
  gemm_lds3_kernel<0, 2, 2, 256><<<dim3((N + 127) / 128, 3), 256, 0, stream>>>(
      Xbf, Xbf + HS, Xbf + 2 * HS, Wt + 3 * 262144, 32768, Hbuf, HS, dinv_all, N, 256, 128);
  // ---- layer 2 agg fused with layer-3 pooling (X2 never materialized) ----
  agg3_kernel<2, 1><<<dim3((N + 15) / 16, 3), 256, 0, stream>>>(
      Hbuf, HS, rowptr, csr, Es[0], Es[1], dinv_all, Bp[1], gp[1], btp[1], mp[1], vp[1], Xbf,
      HS, c_all, pooled_rep, N);

  head_kernel<<<1, 192, 0, stream>>>(pooled_rep, W3p, B3p, g3p, bt3p, m3p, v3p, fuse_W, fuse_b,
                                     cls_W, cls_b, reg_W, reg_b, (float*)d_out);
}

// Round 19
// 586.328 us; speedup vs baseline: 1.2265x; 1.0131x over previous
//
#include <hip/hip_runtime.h>
#include <cstdint>
#include <cstddef>

#define NNODES 50000

typedef __attribute__((ext_vector_type(8))) short short8;
typedef __attribute__((ext_vector_type(4))) float f32x4;
typedef __attribute__((ext_vector_type(4))) unsigned short u16x4;
typedef __attribute__((ext_vector_type(2))) unsigned short u16x2;
typedef __attribute__((ext_vector_type(4))) unsigned int u32x4;

__device__ __forceinline__ unsigned short f2bf(float f) {
  unsigned u = __builtin_bit_cast(unsigned, f);
  u = u + 0x7FFFu + ((u >> 16) & 1u);
  return (unsigned short)(u >> 16);
}
__device__ __forceinline__ float bf2f(unsigned short u) {
  return __builtin_bit_cast(float, (unsigned)u << 16);
}
// HW packed fp32->bf16 (RNE), gfx950: no builtin, inline asm (T12 recipe)
__device__ __forceinline__ unsigned cvtpk(float lo, float hi) {
  unsigned r;
  asm("v_cvt_pk_bf16_f32 %0, %1, %2" : "=v"(r) : "v"(lo), "v"(hi));
  return r;
}

// ---------------- batched degree count (grid.y = scale) ----------------
__global__ void deg_count3_kernel(const int* __restrict__ e0, const int* __restrict__ e1,
                                  const int* __restrict__ e2, int E0, int E1, int E2,
                                  int* __restrict__ deg, int n) {
  int s = blockIdx.y;
  const int* ei = s == 0 ? e0 : (s == 1 ? e1 : e2);
  int E = s == 0 ? E0 : (s == 1 ? E1 : E2);
  int i = blockIdx.x * blockDim.x + threadIdx.x;
  if (i < E) atomicAdd(&deg[(size_t)s * n + ei[E + i]], 1);
}

// ---------------- two-level parallel scan: bsum -> bscan -> rowptr(+dinv) ----------------
__global__ void bsum_kernel(const int* __restrict__ deg, int* __restrict__ bsum, int n,
                            int nchunk) {
  int s = blockIdx.y, c = blockIdx.x;
  int i = c * 256 + threadIdx.x;
  int v = (i < n) ? deg[(size_t)s * n + i] : 0;
  __shared__ int red[256];
  red[threadIdx.x] = v;
  __syncthreads();
  for (int o = 128; o > 0; o >>= 1) {
    if (threadIdx.x < o) red[threadIdx.x] += red[threadIdx.x + o];
    __syncthreads();
  }
  if (threadIdx.x == 0) bsum[s * nchunk + c] = red[0];
}

__global__ void bscan_kernel(int* __restrict__ bsum, int nchunk) {  // grid 3
  int s = blockIdx.x;
  __shared__ int tmp[256];
  int v = (threadIdx.x < nchunk) ? bsum[s * nchunk + threadIdx.x] : 0;
  tmp[threadIdx.x] = v;
  __syncthreads();
  for (int o = 1; o < 256; o <<= 1) {
    int t = (threadIdx.x >= o) ? tmp[threadIdx.x - o] : 0;
    __syncthreads();
    tmp[threadIdx.x] += t;
    __syncthreads();
  }
  if (threadIdx.x < nchunk) bsum[s * nchunk + threadIdx.x] = tmp[threadIdx.x] - v;  // exclusive
}

// rowptr + cursor + dinv (deg_finish folded in: dinv = rsqrt(deg+1))
__global__ void rowptr_kernel(const int* __restrict__ deg, const int* __restrict__ bsum,
                              int* __restrict__ rowptr, int* __restrict__ cursor,
                              float* __restrict__ dinv, int n, int nchunk) {
  int s = blockIdx.y, c = blockIdx.x;
  int i = c * 256 + threadIdx.x;
  int v = (i < n) ? deg[(size_t)s * n + i] : 0;
  __shared__ int tmp[256];
  tmp[threadIdx.x] = v;
  __syncthreads();
  for (int o = 1; o < 256; o <<= 1) {
    int t = (threadIdx.x >= o) ? tmp[threadIdx.x - o] : 0;
    __syncthreads();
    tmp[threadIdx.x] += t;
    __syncthreads();
  }
  int incl = tmp[threadIdx.x] + bsum[s * nchunk + c];
  if (i < n) {
    rowptr[(size_t)s * (n + 1) + i + 1] = incl;
    cursor[(size_t)s * n + i] = incl - v;
    dinv[(size_t)s * n + i] = rsqrtf((float)v + 1.0f);  // +1 self-loop
  }
  if (i == 0) rowptr[(size_t)s * (n + 1)] = 0;
}

// ---------------- batched CSR fill + fused pool-weight accumulate ----------------
// One edge pass: csr[pos]=src AND csum[src] += dinv[dst].
__global__ void csr_fill3_kernel(const int* __restrict__ e0, const int* __restrict__ e1,
                                 const int* __restrict__ e2, int E0, int E1, int E2,
                                 int* __restrict__ cursor, int* __restrict__ csr,
                                 const float* __restrict__ dinv_all, float* __restrict__ csum,
                                 int n) {
  int s = blockIdx.y;
  const int* ei = s == 0 ? e0 : (s == 1 ? e1 : e2);
  int E = s == 0 ? E0 : (s == 1 ? E1 : E2);
  int coff = (s > 0 ? E0 : 0) + (s > 1 ? E1 : 0);
  int i = blockIdx.x * blockDim.x + threadIdx.x;
  if (i < E) {
    int src = ei[i];
    int dst = ei[E + i];
    int pos = atomicAdd(&cursor[(size_t)s * n + dst], 1);
    csr[coff + pos] = src;
    unsafeAtomicAdd(&csum[(size_t)s * n + src], dinv_all[(size_t)s * n + dst]);
  }
}

// ---------------- batched weight transpose ----------------
__global__ void wt_all_kernel(const float* __restrict__ W0, const float* __restrict__ W1,
                              unsigned short* __restrict__ Wt) {
  int idx = blockIdx.x * blockDim.x + threadIdx.x;
  const int L0TOT = 3 * 262144;
  const int TOT = L0TOT + 3 * 32768;
  if (idx >= TOT) return;
  if (idx < L0TOT) {
    int s = idx / 262144, r = idx - s * 262144;
    int n = r >> 10, k = r & 1023;
    Wt[idx] = f2bf(W0[(size_t)s * 262144 + k * 256 + n]);
  } else {
    int j = idx - L0TOT;
    int s = j / 32768, r = j - s * 32768;
    int n = r >> 8, k = r & 255;
    Wt[idx] = f2bf(W1[(size_t)s * 32768 + k * 128 + n]);
  }
}

// ---------------- m97-style MFMA GEMM via global_load_lds (r12-exact, best) ----------------
template <int A_FP32, int WR, int WC, int NT>
__global__ __launch_bounds__(NT) void gemm_lds3_kernel(
    const void* __restrict__ A0v, const void* __restrict__ A1v, const void* __restrict__ A2v,
    const unsigned short* __restrict__ Wt, int wtStride,
    unsigned short* __restrict__ H, size_t hStride,
    const float* __restrict__ dinv_all, int M, int K, int Nc) {
  constexpr int BM = WR * 64;
  constexpr int BN = WC * 64;
  constexpr int ABYTES = BM * 64 * (A_FP32 ? 4 : 2);
  constexpr int BBYTES = BN * 64 * 2;
  constexpr int AISS = ABYTES / (16 * NT);
  constexpr int BISS = BBYTES / (16 * NT);

  __shared__ unsigned char lds[ABYTES + BBYTES];
  float* AldsF = (float*)lds;
  unsigned short* AldsH = (unsigned short*)lds;
  unsigned short* Blds = (unsigned short*)(lds + ABYTES);

  const int sc = blockIdx.y;
  const void* Av = sc == 0 ? A0v : (sc == 1 ? A1v : A2v);
  const unsigned short* Wts = Wt + (size_t)sc * wtStride;
  unsigned short* Hs = H + (size_t)sc * hStride;
  const float* dinv = dinv_all + (size_t)sc * M;
  const int tid = threadIdx.x;
  const int lane = tid & 63;
  const int w = tid >> 6;
  const int wr = w / WC;
  const int wc = w - wr * WC;
  const int r0 = blockIdx.x * BM;
  const float* Af = (const float*)Av;
  const unsigned short* Ab = (const unsigned short*)Av;
  const int NT16 = K >> 6;

  f32x4 acc[4][4] = {};

  for (int t = 0; t < NT16; ++t) {
    const int k0 = t << 6;
#pragma unroll
    for (int i = 0; i < AISS; i++) {
      int c = (w * AISS + i) * 64 + lane;
      if constexpr (A_FP32) {
        int row = c >> 4, j = c & 15;
        int gr = r0 + row;
        if (gr > M - 1) gr = M - 1;  // clamp: never stored
        const float* src = Af + (size_t)gr * K + k0 + ((j ^ (row & 7)) << 2);
        __builtin_amdgcn_global_load_lds(
            (const __attribute__((address_space(1))) void*)src,
            (__attribute__((address_space(3))) void*)(lds + (size_t)(w * AISS + i) * 1024),
            16, 0, 0);
      } else {
        int row = c >> 3, j = c & 7;
        int gr = r0 + row;
        if (gr > M - 1) gr = M - 1;
        const unsigned short* src = Ab + (size_t)gr * K + k0 + ((j ^ (row & 7)) << 3);
        __builtin_amdgcn_global_load_lds(
            (const __attribute__((address_space(1))) void*)src,
            (__attribute__((address_space(3))) void*)(lds + (size_t)(w * AISS + i) * 1024),
            16, 0, 0);
      }
    }
#pragma unroll
    for (int i = 0; i < BISS; i++) {
      int c = (w * BISS + i) * 64 + lane;
      int n = c >> 3, j = c & 7;
      const unsigned short* src = Wts + (size_t)n * K + k0 + ((j ^ (n & 7)) << 3);
      __builtin_amdgcn_global_load_lds(
          (const __attribute__((address_space(1))) void*)src,
          (__attribute__((address_space(3))) void*)(lds + ABYTES + (size_t)(w * BISS + i) * 1024),
          16, 0, 0);
    }
    __syncthreads();

#pragma unroll
    for (int kk = 0; kk < 2; kk++) {
      const int t16 = kk * 4 + (lane >> 4);
      short8 af[4], bfr[4];
#pragma unroll
      for (int mi = 0; mi < 4; mi++) {
        int row = wr * 64 + mi * 16 + (lane & 15);
        if constexpr (A_FP32) {
          const float* bp = AldsF + row * 64;
          f32x4 u0 = *(const f32x4*)(bp + ((((2 * t16)) ^ (row & 7)) << 2));
          f32x4 u1 = *(const f32x4*)(bp + (((2 * t16 + 1) ^ (row & 7)) << 2));
          u32x4 p;
          p[0] = cvtpk(u0[0], u0[1]);
          p[1] = cvtpk(u0[2], u0[3]);
          p[2] = cvtpk(u1[0], u1[1]);
          p[3] = cvtpk(u1[2], u1[3]);
          af[mi] = __builtin_bit_cast(short8, p);
        } else {
          af[mi] = *(const short8*)(AldsH + row * 64 + ((t16 ^ (row & 7)) << 3));
        }
      }
#pragma unroll
      for (int ni = 0; ni < 4; ni++) {
        int n = wc * 64 + ni * 16 + (lane & 15);
        bfr[ni] = *(const short8*)(Blds + n * 64 + ((t16 ^ (n & 7)) << 3));
      }
#pragma unroll
      for (int mi = 0; mi < 4; mi++)
#pragma unroll
        for (int ni = 0; ni < 4; ni++)
          acc[mi][ni] =
              __builtin_amdgcn_mfma_f32_16x16x32_bf16(af[mi], bfr[ni], acc[mi][ni], 0, 0, 0);
    }
    __syncthreads();
  }

  // C/D layout: col = lane&15, row = (lane>>4)*4 + reg
#pragma unroll
  for (int mi = 0; mi < 4; mi++) {
#pragma unroll
    for (int r = 0; r < 4; r++) {
      int gr = r0 + wr * 64 + mi * 16 + (lane >> 4) * 4 + r;
      if (gr < M) {
        float di = dinv[gr];
#pragma unroll
        for (int ni = 0; ni < 4; ni++) {
          int col = wc * 64 + ni * 16 + (lane & 15);
          Hs[(size_t)gr * Nc + col] = f2bf(acc[mi][ni][r] * di);
        }
      }
    }
  }
}

// ---------------- batched CSR gather + BN (+ReLU->X | +pool) grid-strided -------------
template <int VEC>
__device__ __forceinline__ void addrow(const unsigned short* __restrict__ p, float* acc) {
  if constexpr (VEC == 4) {
    u16x4 u = *(const u16x4*)p;
#pragma unroll
    for (int j = 0; j < 4; j++) acc[j] += bf2f(u[j]);
  } else {
    u16x2 u = *(const u16x2*)p;
    acc[0] += bf2f(u[0]);
    acc[1] += bf2f(u[1]);
  }
}

// POOL=0: X[row] = relu(bn(agg)) bf16.  POOL=1 (VEC=2): pooled_rep[rep][s][ch] +=
// sum_rows c[row]*relu(bn(agg)); c computed inline = dinv*(dinv+csum)  (c_finish folded).
template <int VEC, int POOL>
__global__ __launch_bounds__(256) void agg3_kernel(
    const unsigned short* __restrict__ Hb, size_t hStride,
    const int* __restrict__ rowptr, const int* __restrict__ csr, int E0, int E1,
    const float* __restrict__ dinv_all,
    const float* __restrict__ Bb, const float* __restrict__ g,
    const float* __restrict__ bt, const float* __restrict__ m,
    const float* __restrict__ v, unsigned short* __restrict__ X, size_t xStride,
    const float* __restrict__ csum_all, float* __restrict__ pooled_rep, int n) {
  const int C = VEC * 64;
  const int sIdx = blockIdx.y;
  const unsigned short* Hs = Hb + (size_t)sIdx * hStride;
  unsigned short* Xs = X + (size_t)sIdx * xStride;
  const int* rp = rowptr + (size_t)sIdx * (n + 1);
  const int* cs = csr + (sIdx > 0 ? E0 : 0) + (sIdx > 1 ? E1 : 0);
  const float* dinv = dinv_all + (size_t)sIdx * n;
  const float* cw = csum_all + (size_t)sIdx * n;
  const int lane = threadIdx.x & 63;
  const int w = threadIdx.x >> 6;
  const int ch = lane * VEC;
  float a[VEC], sh[VEC];
#pragma unroll
  for (int j = 0; j < VEC; j++) {
    float aa = g[sIdx * C + ch + j] * rsqrtf(v[sIdx * C + ch + j] + 1e-5f);
    a[j] = aa;
    sh[j] = (Bb[sIdx * C + ch + j] - m[sIdx * C + ch + j]) * aa + bt[sIdx * C + ch + j];
  }
  float pool[VEC] = {};
  const int stride = gridDim.x * 4;
  for (int row = blockIdx.x * 4 + w; row < n; row += stride) {
    float acc[VEC] = {};
    addrow<VEC>(Hs + (size_t)row * C + ch, acc);  // self
    int b0 = rp[row], b1 = rp[row + 1];
    int i = b0;
    for (; i + 8 <= b1; i += 8) {
      int s0 = cs[i], s1 = cs[i + 1], s2 = cs[i + 2], s3 = cs[i + 3];
      int s4 = cs[i + 4], s5 = cs[i + 5], s6 = cs[i + 6], s7 = cs[i + 7];
      addrow<VEC>(Hs + (size_t)s0 * C + ch, acc);
      addrow<VEC>(Hs + (size_t)s1 * C + ch, acc);
      addrow<VEC>(Hs + (size_t)s2 * C + ch, acc);
      addrow<VEC>(Hs + (size_t)s3 * C + ch, acc);
      addrow<VEC>(Hs + (size_t)s4 * C + ch, acc);
      addrow<VEC>(Hs + (size_t)s5 * C + ch, acc);
      addrow<VEC>(Hs + (size_t)s6 * C + ch, acc);
      addrow<VEC>(Hs + (size_t)s7 * C + ch, acc);
    }
    for (; i < b1; i++) addrow<VEC>(Hs + (size_t)cs[i] * C + ch, acc);
    float dd = dinv[row];
    if constexpr (!POOL) {
      if constexpr (VEC == 4) {
        u16x4 o;
#pragma unroll
        for (int j = 0; j < 4; j++) o[j] = f2bf(fmaxf(acc[j] * dd * a[j] + sh[j], 0.0f));
        *(u16x4*)(Xs + (size_t)row * C + ch) = o;
      } else {
        u16x2 o;
        o[0] = f2bf(fmaxf(acc[0] * dd * a[0] + sh[0], 0.0f));
        o[1] = f2bf(fmaxf(acc[1] * dd * a[1] + sh[1], 0.0f));
        *(u16x2*)(Xs + (size_t)row * C + ch) = o;
      }
    } else {
      float cr = dd * (dd + cw[row]);  // c = dinv*(dinv + sum_dinv_dst), inline
#pragma unroll
      for (int j = 0; j < VEC; j++)
        pool[j] += cr * fmaxf(acc[j] * dd * a[j] + sh[j], 0.0f);  // X2 = relu(bn(.))
    }
  }
  if constexpr (POOL) {
    __shared__ float red[4 * 128];
#pragma unroll
    for (int j = 0; j < VEC; j++) red[w * 128 + ch + j] = pool[j];
    __syncthreads();
    int t = threadIdx.x;
    if (t < 128) {
      float val = red[t] + red[128 + t] + red[256 + t] + red[384 + t];
      unsafeAtomicAdd(&pooled_rep[(((size_t)(blockIdx.x & 7) * 3 + sIdx) << 7) + t], val);
    }
  }
}

// ---------------- head: sum replicas; per-scale BN3((pooled/N)@W3+b3), fuse, cls, reg ----
__global__ void head_kernel(const float* __restrict__ pooled_rep, const float* __restrict__ W3p,
                            const float* __restrict__ B3p, const float* __restrict__ g3p,
                            const float* __restrict__ bt3p, const float* __restrict__ m3p,
                            const float* __restrict__ v3p, const float* __restrict__ fuse_W,
                            const float* __restrict__ fuse_b, const float* __restrict__ cls_W,
                            const float* __restrict__ cls_b, const float* __restrict__ reg_W,
                            const float* __restrict__ reg_b, float* __restrict__ out) {
  __shared__ float pv[3 * 128];
  __shared__ float e[192];
  __shared__ float fused[64];
  int t = threadIdx.x;
  for (int idx = t; idx < 384; idx += 192) {
    int s = idx >> 7, k = idx & 127;
    float acc = 0.0f;
#pragma unroll
    for (int r = 0; r < 8; r++) acc += pooled_rep[((r * 3 + s) << 7) + k];
    pv[idx] = acc;
  }
  __syncthreads();
  if (t < 192) {
    int s = t >> 6, ch = t & 63;
    float acc = 0.0f;
    const float* W3 = W3p + (size_t)s * 128 * 64;
    for (int k = 0; k < 128; k++) acc += pv[s * 128 + k] * W3[k * 64 + ch];
    float a3 = g3p[s * 64 + ch] * rsqrtf(v3p[s * 64 + ch] + 1e-5f);
    e[t] = (acc * (1.0f / (float)NNODES) + B3p[s * 64 + ch] - m3p[s * 64 + ch]) * a3 +
           bt3p[s * 64 + ch];
  }
  __syncthreads();
  if (t < 64) {
    float acc = fuse_b[t];
    for (int k = 0; k < 192; k++) acc += e[k] * fuse_W[k * 64 + t];
    fused[t] = fmaxf(acc, 0.0f);
  }
  __syncthreads();
  if (t < 10) {
    float acc = cls_b[t];
    for (int k = 0; k < 64; k++) acc += fused[k] * cls_W[k * 10 + t];
    out[t] = acc;
  }
  if (t == 64) {
    float acc = reg_b[0];
    for (int k = 0; k < 64; k++) acc += fused[k] * reg_W[k];
    out[10] = 1.0f / (1.0f + expf(-acc));
  }
}

extern "C" void kernel_launch(void* const* d_in, const int* in_sizes, int n_in,
                              void* d_out, int out_size, void* d_ws, size_t ws_size,
                              hipStream_t stream) {
  const int N = NNODES;
  const int NCHUNK = (N + 255) / 256;  // 196
  const float* xs[3] = {(const float*)d_in[0], (const float*)d_in[1], (const float*)d_in[2]};
  const int* eis[3] = {(const int*)d_in[3], (const int*)d_in[4], (const int*)d_in[5]};
  int Es[3];
  for (int s = 0; s < 3; s++) Es[s] = in_sizes[3 + s] / 2;
  int maxE = Es[0] > Es[1] ? Es[0] : Es[1];
  if (Es[2] > maxE) maxE = Es[2];

  const float* Wp[2]  = {(const float*)d_in[6],  (const float*)d_in[12]};
  const float* Bp[2]  = {(const float*)d_in[7],  (const float*)d_in[13]};
  const float* gp[2]  = {(const float*)d_in[8],  (const float*)d_in[14]};
  const float* btp[2] = {(const float*)d_in[9],  (const float*)d_in[15]};
  const float* mp[2]  = {(const float*)d_in[10], (const float*)d_in[16]};
  const float* vp[2]  = {(const float*)d_in[11], (const float*)d_in[17]};
  const float* W3p  = (const float*)d_in[18];
  const float* B3p  = (const float*)d_in[19];
  const float* g3p  = (const float*)d_in[20];
  const float* bt3p = (const float*)d_in[21];
  const float* m3p  = (const float*)d_in[22];
  const float* v3p  = (const float*)d_in[23];
  const float* fuse_W = (const float*)d_in[24];
  const float* fuse_b = (const float*)d_in[25];
  const float* cls_W  = (const float*)d_in[26];
  const float* cls_b  = (const float*)d_in[27];
  const float* reg_W  = (const float*)d_in[28];
  const float* reg_b  = (const float*)d_in[29];

  size_t off = 0;
  auto alloc = [&](size_t nbytes) {
    char* p = (char*)d_ws + off;
    off += (nbytes + 255) & ~(size_t)255;
    return (void*)p;
  };
  // zero-init region (one memset covers deg + csum + pooled_rep)
  size_t zOff = off;
  int*   deg        = (int*)alloc(3 * (size_t)N * 4);
  float* csum_all   = (float*)alloc(3 * (size_t)N * 4);
  float* pooled_rep = (float*)alloc(8 * 3 * 128 * 4);
  size_t zBytes = off - zOff;
  float* dinv_all   = (float*)alloc(3 * (size_t)N * 4);
  int*   bsum       = (int*)alloc(3 * (size_t)NCHUNK * 4);
  int*   rowptr     = (int*)alloc(3 * (size_t)(N + 1) * 4);
  int*   cursor     = (int*)alloc(3 * (size_t)N * 4);
  int*   csr        = (int*)alloc((size_t)(Es[0] + Es[1] + Es[2]) * 4);
  unsigned short* Hbuf = (unsigned short*)alloc(3 * (size_t)N * 256 * 2);  // 76.8 MB
  unsigned short* Xbf  = (unsigned short*)alloc(3 * (size_t)N * 256 * 2);  // 76.8 MB
  unsigned short* Wt   = (unsigned short*)alloc((size_t)(3 * 262144 + 3 * 32768) * 2);
  (void)ws_size; (void)n_in; (void)out_size;

  const size_t HS = (size_t)N * 256;  // per-scale stride for Hbuf/Xbf (elements)

  hipMemsetAsync((char*)d_ws + zOff, 0, zBytes, stream);  // deg + csum + pooled_rep

  // ---- graph prep (batched; dinv folded into rowptr; csum folded into fill) ----
  dim3 eg((maxE + 255) / 256, 3);
  deg_count3_kernel<<<eg, 256, 0, stream>>>(eis[0], eis[1], eis[2], Es[0], Es[1], Es[2], deg, N);
  bsum_kernel<<<dim3(NCHUNK, 3), 256, 0, stream>>>(deg, bsum, N, NCHUNK);
  bscan_kernel<<<3, 256, 0, stream>>>(bsum, NCHUNK);
  rowptr_kernel<<<dim3(NCHUNK, 3), 256, 0, stream>>>(deg, bsum, rowptr, cursor, dinv_all, N,
                                                     NCHUNK);
  csr_fill3_kernel<<<eg, 256, 0, stream>>>(eis[0], eis[1], eis[2], Es[0], Es[1], Es[2], cursor,
                                           csr, dinv_all, csum_all, N);
  wt_all_kernel<<<(3 * 262144 + 3 * 32768 + 255) / 256, 256, 0, stream>>>(Wp[0], Wp[1], Wt);

  // ---- layer 0: K=1024, C=256; BM=64 BN=256, 48KB LDS (r12-exact) ----
  gemm_lds3_kernel<1, 1, 4, 256><<<dim3((N + 63) / 64, 3), 256, 0, stream>>>(
      xs[0], xs[1], xs[2], Wt, 262144, Hbuf, HS, dinv_all, N, 1024, 256);
  agg3_kernel<4, 0><<<dim3((N + 15) / 16, 3), 256, 0, stream>>>(
      Hbuf, HS, rowptr, csr, Es[0], Es[1], dinv_all, Bp[0], gp[0], btp[0], mp[0], vp[0], Xbf,
      HS, csum_all, pooled_rep, N);

  // ---- layer 1: K=256, C=128; BM=128 BN=128, 32KB LDS (r12-exact) ----
  gemm_lds3_kernel<0, 2, 2, 256><<<dim3((N + 127) / 128, 3), 256, 0, stream>>>(
      Xbf, Xbf + HS, Xbf + 2 * HS, Wt + 3 * 262144, 32768, Hbuf, HS, dinv_all, N, 256, 128);
  // ---- layer 2 agg fused with layer-3 pooling (X2 never materialized; c inline) ----
  agg3_kernel<2, 1><<<dim3((N + 15) / 16, 3), 256, 0, stream>>>(
      Hbuf, HS, rowptr, csr, Es[0], Es[1], dinv_all, Bp[1], gp[1], btp[1], mp[1], vp[1], Xbf,
      HS, csum_all, pooled_rep, N);

  head_kernel<<<1, 192, 0, stream>>>(pooled_rep, W3p, B3p, g3p, bt3p, m3p, v3p, fuse_W, fuse_b,
                                     cls_W, cls_b, reg_W, reg_b, (float*)d_out);
}